// Round 2
// baseline (11822.891 us; speedup 1.0000x reference)
//
#include <hip/hip_runtime.h>

typedef __attribute__((ext_vector_type(8))) short short8;
typedef __attribute__((ext_vector_type(4))) float f32x4;
typedef __attribute__((ext_vector_type(4))) int int4v;

#define HD 1024
#define BD 64
#define TD 512
#define BH 65536UL  // one h slot: 64*1024
#define NBLK 194

// ---------------- workspace layout ----------------
#define M4 4194304UL
#define OFF_WHH0 0UL
#define OFF_WIH1 (1UL * M4)
#define OFF_WHH1 (2UL * M4)
#define OFF_WIH2 (3UL * M4)
#define OFF_WHH2 (4UL * M4)
#define OFF_WOUT (5UL * M4)                 // 128 x 1024 (padded rows zeroed)
#define OFF_H0   (OFF_WOUT + 131072UL)      // [4 slots][64][1024] each layer
#define OFF_H1   (OFF_H0 + 262144UL)
#define OFF_H2   (OFF_H1 + 262144UL)
#define USHORT_TOTAL (OFF_H2 + 262144UL)    // 21889024
#define FBYTE_BASE (USHORT_TOTAL * 2UL)
#define FOFF_C0 0UL                          // c stored [j][b] (transposed)
#define FOFF_C1 65536UL
#define FOFF_C2 131072UL
#define FOFF_B0 196608UL                     // combined biases b_ih+b_hh [4096]
#define FOFF_B1 200704UL
#define FOFF_B2 204800UL
#define FOFF_BOUT 208896UL                   // [128], pad zeroed
#define FOFF_FLAGS 209024UL                  // int-indexed: 4 layers x 256 per-wave flags
#define PREP_TOTAL 22099072UL

__device__ __forceinline__ unsigned short f2bf(float f) {
  union { float f; unsigned u; } v; v.f = f;
  unsigned r = v.u + 0x7fffu + ((v.u >> 16) & 1u);  // RNE
  return (unsigned short)(r >> 16);
}
__device__ __forceinline__ float sigmoidf_(float x) {
  return 1.0f / (1.0f + __expf(-x));
}
// LDS bank swizzle: inject gn's high bits into bank bits 0-1 and gn&7 into
// bits 2-4. Writes: ~4-way (was 8-way). Reads (fixed gn, consecutive b):
// b^const is a permutation -> 2-way (free).
__device__ __forceinline__ int sw(int gn, int b) {
  return gn * 64 + (b ^ (((gn & 7) << 2) | ((gn >> 3) & 3)));
}

// A-matrix load: PLAIN CACHED 16B load (L1/L2). Cross-XCD freshness is
// guaranteed by the per-step agent acquire fence (buffer_inv) executed after
// the flag-wait and before any A-load: producer drains sc1 h-stores to MALL
// before publishing its flag, consumer invalidates stale clean lines after
// seeing the flag. Volatile asm => program-order issue among themselves;
// vmcnt managed explicitly by AWAIT_N.
__device__ __forceinline__ void gload16(int4v& dst, const unsigned short* p) {
  asm volatile("global_load_dwordx4 %0, %1, off" : "=v"(dst) : "v"(p));
}
#define AWAIT_N(N, a0, a1, a2, a3) \
  asm volatile("s_waitcnt vmcnt(" #N ")" : "+v"(a0), "+v"(a1), "+v"(a2), "+v"(a3))

// ---------------- distributed flag "barrier" ----------------
// Per-wave progress flags, one 256-int array per layer (real entries 0 for
// layers 0-2; out-layer has 8 real + 248 entries preset to 2^29 by prep).
// Signal: ONE plain sc1 store per wave (no RMW -> no serialization).
// Wait: ONE dwordx4 per lane covers all 256 flags; min4 + __all ballot.
// Flag loads stay sc1 (must bypass L2 to see remote stores every poll).
__device__ __forceinline__ void fload4(int4v& v, const int* p) {
  asm volatile("global_load_dwordx4 %0, %1, off sc1" : "=v"(v) : "v"(p));
  asm volatile("s_waitcnt vmcnt(0)" : "+v"(v));
}
__device__ __forceinline__ bool all_ge(const int4v& v, int k) {
  int a = v[0] < v[1] ? v[0] : v[1];
  int b = v[2] < v[3] ? v[2] : v[3];
  int m = a < b ? a : b;
  return __all(m >= k) != 0;
}
__device__ __forceinline__ void wait_ge(const int* f, int lane, int k) {
  const int* p = f + lane * 4;
  for (;;) {
    int4v v; fload4(v, p);
    if (all_ge(v, k)) return;
    __builtin_amdgcn_s_sleep(1);
  }
}
__device__ __forceinline__ void wait_ge2(const int* fa, int ka, const int* fb, int kb, int lane) {
  const int* pa = fa + lane * 4;
  const int* pb = fb + lane * 4;
  for (;;) {
    int4v va, vb;
    asm volatile("global_load_dwordx4 %0, %1, off sc1" : "=v"(va) : "v"(pa));
    asm volatile("global_load_dwordx4 %0, %1, off sc1" : "=v"(vb) : "v"(pb));
    asm volatile("s_waitcnt vmcnt(0)" : "+v"(va), "+v"(vb));
    if (all_ge(va, ka) && all_ge(vb, kb)) return;
    __builtin_amdgcn_s_sleep(1);
  }
}

// ---------------- prep ----------------
__global__ void prep_kernel(const float* __restrict__ Whh0, const float* __restrict__ Wih1,
                            const float* __restrict__ Whh1, const float* __restrict__ Wih2,
                            const float* __restrict__ Whh2, const float* __restrict__ Wout,
                            const float* __restrict__ bih0, const float* __restrict__ bhh0,
                            const float* __restrict__ bih1, const float* __restrict__ bhh1,
                            const float* __restrict__ bih2, const float* __restrict__ bhh2,
                            const float* __restrict__ bout, void* wsv) {
  unsigned short* u = (unsigned short*)wsv;
  float* fr = (float*)((char*)wsv + FBYTE_BASE);
  int* fi = (int*)fr;
  size_t stride = (size_t)gridDim.x * blockDim.x;
  for (size_t i = (size_t)blockIdx.x * blockDim.x + threadIdx.x; i < PREP_TOTAL; i += stride) {
    if (i < 20971520UL) {
      size_t which = i >> 22;
      size_t off = i & (M4 - 1UL);
      const float* src = (which == 0) ? Whh0 : (which == 1) ? Wih1 :
                         (which == 2) ? Whh1 : (which == 3) ? Wih2 : Whh2;
      u[i] = f2bf(src[off]);
    } else if (i < 21102592UL) {
      size_t k = i - 20971520UL;
      size_t o = k >> 10, kk = k & 1023UL;
      u[i] = (o < 121) ? f2bf(Wout[o * 1024UL + kk]) : (unsigned short)0;
    } else if (i < 21889024UL) {
      u[i] = 0;                                   // zero all 4 h slots x 3 layers
    } else if (i < 22085632UL) {
      fr[i - 21889024UL] = 0.0f;                  // zero c0,c1,c2
    } else if (i < 22097920UL) {
      size_t k = i - 22085632UL;
      size_t l = k >> 12, n = k & 4095UL;
      const float* bi = (l == 0) ? bih0 : (l == 1) ? bih1 : bih2;
      const float* bh = (l == 0) ? bhh0 : (l == 1) ? bhh1 : bhh2;
      fr[FOFF_B0 + l * 4096UL + n] = bi[n] + bh[n];
    } else if (i < 22098048UL) {
      size_t k = i - 22097920UL;
      fr[FOFF_BOUT + k] = (k < 121) ? bout[k] : 0.0f;
    } else {
      size_t k = i - 22098048UL;                  // flags: layers 0-2 full, out 8 real
      fi[FOFF_FLAGS + k] = (k < 776UL) ? 0 : (1 << 29);
    }
  }
}

// ---------------- GEMM slice: register B, 6-deep explicit-vmcnt pipelined A ----------------
template <int NK>
__device__ __forceinline__ void gemm_bw(const unsigned short* __restrict__ arow,
                                        const short8 (&bw)[NK][4],
                                        f32x4 (&acc)[4][4]) {
  static_assert(NK >= 6, "pipeline depth");
  int4v ap[6][4];
#pragma unroll
  for (int g = 0; g < 6; ++g)
#pragma unroll
    for (int mt = 0; mt < 4; ++mt)
      gload16(ap[g][mt], arow + mt * 16 * HD + g * 32);
#pragma unroll
  for (int k = 0; k < NK; ++k) {
    const int s = k % 6;
    if (k <= NK - 6)          { AWAIT_N(20, ap[s][0], ap[s][1], ap[s][2], ap[s][3]); }
    else if (NK - 1 - k == 4) { AWAIT_N(16, ap[s][0], ap[s][1], ap[s][2], ap[s][3]); }
    else if (NK - 1 - k == 3) { AWAIT_N(12, ap[s][0], ap[s][1], ap[s][2], ap[s][3]); }
    else if (NK - 1 - k == 2) { AWAIT_N(8,  ap[s][0], ap[s][1], ap[s][2], ap[s][3]); }
    else if (NK - 1 - k == 1) { AWAIT_N(4,  ap[s][0], ap[s][1], ap[s][2], ap[s][3]); }
    else                      { AWAIT_N(0,  ap[s][0], ap[s][1], ap[s][2], ap[s][3]); }
#pragma unroll
    for (int mt = 0; mt < 4; ++mt) {
      short8 a = *(short8*)&ap[s][mt];
#pragma unroll
      for (int ns = 0; ns < 4; ++ns)
        acc[ns][mt] = __builtin_amdgcn_mfma_f32_16x16x32_bf16(a, bw[k][ns], acc[ns][mt], 0, 0, 0);
    }
    if (k + 6 < NK) {
#pragma unroll
      for (int mt = 0; mt < 4; ++mt)
        gload16(ap[s][mt], arow + mt * 16 * HD + (k + 6) * 32);
    }
  }
}

// ---------------- persistent-weight layer driver (dataflow-synced) ----------------
// RAW: own-layer flags >= t (recurrent all-to-all), producer flags >= t+1.
// WAR: 4-deep h slots; writing h[t] destroys h[t-4] -> consumer flags >= t-3,
// probed non-blockingly before the GEMM (monotonic), re-polled (rare) before store.
// Coherence: A-reads are cached; agent acquire fence (buffer_inv) after the
// flag-waits invalidates stale clean L1/L2 lines each step.
template <bool L0L>
__device__ __forceinline__ void run_layer(
    int wgl, int tid,
    const unsigned short* __restrict__ hinbase,  // upstream h (4 slots), null for L0
    unsigned short* __restrict__ hbase,          // own h (4 slots)
    float* __restrict__ c,                       // [1024][64] fp32 transposed
    const unsigned short* __restrict__ Wih,      // null for L0
    const unsigned short* __restrict__ Whh,
    const float* __restrict__ bias,
    const float* __restrict__ strokes,           // L0 only
    const float* __restrict__ Wih0,              // L0 only, fp32 [4096][3]
    float* gbuf, int* fOwn, const int* fProd, const int* fCons) {
  constexpr int NK = L0L ? 8 : 16;
  const int lane = tid & 63;
  const int w = tid >> 6;
  const int nl = lane & 15;
  const int kq8 = (lane >> 4) << 3;

  const unsigned short* Wm;
  int k0beg;
  bool useHin;
  if (L0L) { Wm = Whh; k0beg = w * 256; useHin = false; }
  else     { Wm = (w < 2) ? Wih : Whh; k0beg = (w & 1) * 512; useHin = (w < 2); }

  short8 bw[NK][4];
#pragma unroll
  for (int ns = 0; ns < 4; ++ns) {
    int jgl = wgl * 16 + ns * 4 + (nl >> 2);
    int row = (nl & 3) * HD + jgl;                 // gate-major weight row
    const unsigned short* wr = Wm + (size_t)row * HD + kq8 + k0beg;
#pragma unroll
    for (int k = 0; k < NK; ++k) bw[k][ns] = *(const short8*)(wr + k * 32);
  }

  const int myf = wgl * 4 + w;
  const int bb = (lane >> 4) << 2;
  float* gs = gbuf + w * 4096;

  for (int t = 0; t < TD; ++t) {
    // ---- RAW waits (all waves poll independently; ends with vmcnt==0) ----
    if (L0L) {
      if (t > 0) wait_ge(fOwn, lane, t);
    } else {
      if (t > 0) wait_ge2(fOwn, t, fProd, t + 1, lane);
      else       wait_ge(fProd, lane, 1);
    }
    // ---- WAR early probe (check-early/use-late; flags are monotonic) ----
    bool war_ok = true;
    if (t >= 4) { int4v v; fload4(v, fCons + lane * 4); war_ok = all_ge(v, t - 3); }

    // Invalidate stale clean L1/L2 lines so cached A-reads see the h data the
    // producers drained to MALL before publishing their flags. Dirty lines
    // (our c-state) are preserved by an acquire invalidate.
    __builtin_amdgcn_fence(__ATOMIC_ACQUIRE, "agent");

    const unsigned short* A = useHin ? (hinbase + (size_t)(t & 3) * BH)
                                     : (hbase + (size_t)((t - 1) & 3) * BH);
    const unsigned short* arow = A + nl * HD + kq8 + k0beg;

    f32x4 acc[4][4];
    const f32x4 z4 = {0.f, 0.f, 0.f, 0.f};
#pragma unroll
    for (int ns = 0; ns < 4; ++ns)
#pragma unroll
      for (int mt = 0; mt < 4; ++mt) acc[ns][mt] = z4;

    gemm_bw<NK>(arow, bw, acc);

#pragma unroll
    for (int ns = 0; ns < 4; ++ns) {
      int gn = ns * 16 + nl;
#pragma unroll
      for (int mt = 0; mt < 4; ++mt)
#pragma unroll
        for (int r = 0; r < 4; ++r)
          gs[sw(gn, mt * 16 + bb + r)] = acc[ns][mt][r];
    }
    __syncthreads();

    // rare path: consumer of the slot we're about to overwrite still reading
    if (!war_ok) wait_ge(fCons, lane, t - 3);

    unsigned short* hout = hbase + (size_t)(t & 3) * BH;
#pragma unroll
    for (int it = 0; it < 2; ++it) {
      int item = it * 256 + tid;
      int jp = item >> 6;          // 0..7 pair of j
      int b = item & 63;
      unsigned hv[2];
#pragma unroll
      for (int u2 = 0; u2 < 2; ++u2) {
        int jj = jp * 2 + u2;
        int j = wgl * 16 + jj;
        float p[4];
#pragma unroll
        for (int g = 0; g < 4; ++g) {
          int a = sw(jj * 4 + g, b);
          p[g] = gbuf[a] + gbuf[4096 + a] + gbuf[8192 + a] + gbuf[12288 + a] + bias[g * HD + j];
        }
        if (L0L) {
          const float* xr = strokes + ((size_t)b * TD + t) * 3;
          float x0 = xr[0], x1 = xr[1], x2 = xr[2];
#pragma unroll
          for (int g = 0; g < 4; ++g) {
            const float* wr = Wih0 + (size_t)(g * HD + j) * 3;
            p[g] += x0 * wr[0] + x1 * wr[1] + x2 * wr[2];
          }
        }
        float iv = sigmoidf_(p[0]);
        float fv = sigmoidf_(p[1]);
        float gv = tanhf(p[2]);
        float ov = sigmoidf_(p[3]);
        int ci = j * BD + b;       // CU-private, normal cached RMW
        float cn = fv * c[ci] + iv * gv;
        c[ci] = cn;
        hv[u2] = (unsigned)f2bf(ov * tanhf(cn));
      }
      unsigned packed = hv[0] | (hv[1] << 16);
      __hip_atomic_store((unsigned*)(hout + (size_t)b * HD + wgl * 16 + jp * 2), packed,
                         __ATOMIC_RELAXED, __HIP_MEMORY_SCOPE_AGENT);
    }
    // drain own h stores to agent scope, then publish per-wave progress flag
    asm volatile("s_waitcnt vmcnt(0)" ::: "memory");
    if (lane == 0)
      __hip_atomic_store(fOwn + myf, t + 1, __ATOMIC_RELAXED, __HIP_MEMORY_SCOPE_AGENT);
    __syncthreads();  // gbuf WAR for next iteration
  }
}

// ---------------- output projection driver (2 WGs x 64 o-columns) ----------------
__device__ __forceinline__ void run_out(
    int wgo, int tid,
    const unsigned short* __restrict__ h2base,
    const unsigned short* __restrict__ Wo,   // bf16 [128][1024] padded
    const float* __restrict__ bo,
    float* __restrict__ outp, float* gbuf, int* fOwn, const int* fProd) {
  const int lane = tid & 63;
  const int w = tid >> 6;
  const int nl = lane & 15;
  const int kq8 = (lane >> 4) << 3;
  const int k0beg = w * 256;

  short8 bw[8][4];
#pragma unroll
  for (int ns = 0; ns < 4; ++ns) {
    int o = wgo * 64 + ns * 16 + nl;
    const unsigned short* wr = Wo + (size_t)o * HD + kq8 + k0beg;
#pragma unroll
    for (int k = 0; k < 8; ++k) bw[k][ns] = *(const short8*)(wr + k * 32);
  }

  const int myf = wgo * 4 + w;
  const int bb = (lane >> 4) << 2;
  float* gs = gbuf + w * 4096;

  for (int t = 0; t < TD; ++t) {
    wait_ge(fProd, lane, t + 1);   // h2[t] published

    __builtin_amdgcn_fence(__ATOMIC_ACQUIRE, "agent");

    const unsigned short* arow = h2base + (size_t)(t & 3) * BH + nl * HD + kq8 + k0beg;

    f32x4 acc[4][4];
    const f32x4 z4 = {0.f, 0.f, 0.f, 0.f};
#pragma unroll
    for (int ns = 0; ns < 4; ++ns)
#pragma unroll
      for (int mt = 0; mt < 4; ++mt) acc[ns][mt] = z4;

    gemm_bw<8>(arow, bw, acc);

#pragma unroll
    for (int ns = 0; ns < 4; ++ns) {
      int gn = ns * 16 + nl;
#pragma unroll
      for (int mt = 0; mt < 4; ++mt)
#pragma unroll
        for (int r = 0; r < 4; ++r)
          gs[sw(gn, mt * 16 + bb + r)] = acc[ns][mt][r];
    }
    __syncthreads();

#pragma unroll
    for (int it = 0; it < 16; ++it) {
      int item = it * 256 + tid;
      int ol = item >> 6;
      int b = item & 63;
      int o = wgo * 64 + ol;
      int a = sw(ol, b);
      float v = gbuf[a] + gbuf[4096 + a] + gbuf[8192 + a] + gbuf[12288 + a] + bo[o];
      if (o < 121) outp[((size_t)b * TD + t) * 121 + o] = v;
    }
    // A-reads of h2[t] fully retired (gemm_bw drains to vmcnt 0) -> signal
    // L2's WAR consumers. outp stores may still be in flight (irrelevant).
    if (lane == 0)
      __hip_atomic_store(fOwn + myf, t + 1, __ATOMIC_RELAXED, __HIP_MEMORY_SCOPE_AGENT);
    __syncthreads();  // gbuf WAR
  }
}

// ---------------- main kernel ----------------
// WGs 0..63 layer0, 64..127 layer1, 128..191 layer2, 192..193 out-proj.
// Plain launch; 194 blocks <= 256 CUs, co-resident (dataflow waits require it,
// same co-residency contract as the previous global-barrier version).
__global__ void __launch_bounds__(256, 1)
lstm_main(const float* __restrict__ strokes, const float* __restrict__ Wih0,
          float* __restrict__ outp, void* __restrict__ wsv) {
  __shared__ float gbuf[16384];  // 64 KB: 4 K-slices x [64 gn][64 b]
  unsigned short* u = (unsigned short*)wsv;
  float* fr = (float*)((char*)wsv + FBYTE_BASE);
  int* flags = (int*)fr + FOFF_FLAGS;
  int* f0 = flags;
  int* f1 = flags + 256;
  int* f2 = flags + 512;
  int* f3 = flags + 768;

  const int wg = blockIdx.x;
  const int tid = threadIdx.x;

  if (wg < 64) {
    run_layer<true>(wg, tid, nullptr, u + OFF_H0, fr + FOFF_C0,
                    nullptr, u + OFF_WHH0, fr + FOFF_B0, strokes, Wih0, gbuf,
                    f0, nullptr, f1);
  } else if (wg < 128) {
    run_layer<false>(wg - 64, tid, u + OFF_H0, u + OFF_H1, fr + FOFF_C1,
                     u + OFF_WIH1, u + OFF_WHH1, fr + FOFF_B1, nullptr, nullptr, gbuf,
                     f1, f0, f2);
  } else if (wg < 192) {
    run_layer<false>(wg - 128, tid, u + OFF_H1, u + OFF_H2, fr + FOFF_C2,
                     u + OFF_WIH2, u + OFF_WHH2, fr + FOFF_B2, nullptr, nullptr, gbuf,
                     f2, f1, f3);
  } else {
    run_out(wg - 192, tid, u + OFF_H2, u + OFF_WOUT, fr + FOFF_BOUT, outp, gbuf,
            f3, f2);
  }
}

extern "C" void kernel_launch(void* const* d_in, const int* in_sizes, int n_in,
                              void* d_out, int out_size, void* d_ws, size_t ws_size,
                              hipStream_t stream) {
  const float* strokes = (const float*)d_in[0];
  const float* Wih0 = (const float*)d_in[1];
  const float* Whh0 = (const float*)d_in[2];
  const float* bih0 = (const float*)d_in[3];
  const float* bhh0 = (const float*)d_in[4];
  const float* Wih1 = (const float*)d_in[5];
  const float* Whh1 = (const float*)d_in[6];
  const float* bih1 = (const float*)d_in[7];
  const float* bhh1 = (const float*)d_in[8];
  const float* Wih2 = (const float*)d_in[9];
  const float* Whh2 = (const float*)d_in[10];
  const float* bih2 = (const float*)d_in[11];
  const float* bhh2 = (const float*)d_in[12];
  const float* Wout = (const float*)d_in[13];
  const float* bout = (const float*)d_in[14];
  float* outp = (float*)d_out;

  hipLaunchKernelGGL(prep_kernel, dim3(4096), dim3(256), 0, stream,
                     Whh0, Wih1, Whh1, Wih2, Whh2, Wout,
                     bih0, bhh0, bih1, bhh1, bih2, bhh2, bout, d_ws);

  hipLaunchKernelGGL(lstm_main, dim3(NBLK), dim3(256), 0, stream,
                     strokes, Wih0, outp, d_ws);
}

// Round 3
// 11125.584 us; speedup vs baseline: 1.0627x; 1.0627x over previous
//
#include <hip/hip_runtime.h>

typedef __attribute__((ext_vector_type(8))) short short8;
typedef __attribute__((ext_vector_type(4))) float f32x4;
typedef __attribute__((ext_vector_type(4))) int int4v;

#define HD 1024
#define BD 64
#define TD 512
#define BH 65536UL  // one h slot: 64*1024 ushorts (128 KB)
#define NS 16       // h slot rotation depth == fence period
#define NBLK 194

// ---------------- workspace layout ----------------
#define M4 4194304UL
#define OFF_WHH0 0UL
#define OFF_WIH1 (1UL * M4)
#define OFF_WHH1 (2UL * M4)
#define OFF_WIH2 (3UL * M4)
#define OFF_WHH2 (4UL * M4)
#define OFF_WOUT (5UL * M4)                 // 128 x 1024 (padded rows zeroed)
#define OFF_H0   (OFF_WOUT + 131072UL)      // [NS slots][64][1024] per layer
#define OFF_H1   (OFF_H0 + (NS * BH))
#define OFF_H2   (OFF_H1 + (NS * BH))
#define USHORT_TOTAL (OFF_H2 + (NS * BH))   // 24248320
#define FBYTE_BASE (USHORT_TOTAL * 2UL)
#define FOFF_C0 0UL                          // c stored [j][b] (transposed)
#define FOFF_C1 65536UL
#define FOFF_C2 131072UL
#define FOFF_B0 196608UL                     // combined biases b_ih+b_hh [4096]
#define FOFF_B1 200704UL
#define FOFF_B2 204800UL
#define FOFF_BOUT 208896UL                   // [128], pad zeroed
#define FOFF_FLAGS 209024UL                  // int-indexed: 4 arrays x 64 per-WG flags
#define PREP_TOTAL 24457600UL

__device__ __forceinline__ unsigned short f2bf(float f) {
  union { float f; unsigned u; } v; v.f = f;
  unsigned r = v.u + 0x7fffu + ((v.u >> 16) & 1u);  // RNE
  return (unsigned short)(r >> 16);
}
__device__ __forceinline__ float sigmoidf_(float x) {
  return 1.0f / (1.0f + __expf(-x));
}
// LDS bank swizzle (unchanged).
__device__ __forceinline__ int sw(int gn, int b) {
  return gn * 64 + (b ^ (((gn & 7) << 2) | ((gn >> 3) & 3)));
}

// A-matrix load: plain cached 16B load (hits XCD L2 when a co-resident WG
// already pulled the line). Freshness: h slot addresses rotate NS=16 deep, so
// a consumer cache can only hold stale data for a line it read >=16 steps ago;
// the per-WG acquire fence every 16 steps invalidates those. Producer side
// guarantees MALL has the data before the flag (release store -> buffer_wbl2).
__device__ __forceinline__ void gload16(int4v& dst, const unsigned short* p) {
  asm volatile("global_load_dwordx4 %0, %1, off" : "=v"(dst) : "v"(p));
}
#define AWAIT_N(N, a0, a1, a2, a3) \
  asm volatile("s_waitcnt vmcnt(" #N ")" : "+v"(a0), "+v"(a1), "+v"(a2), "+v"(a3))

// ---------------- per-WG progress flags ----------------
// One int per WG, 64 per array (out array: 2 real + 62 preset huge).
// Only wave 0 of each WG polls (lane i reads flag i, 4B sc1); other waves
// wait at the following __syncthreads. Signal: ONE release store per WG.
__device__ __forceinline__ void wait1(const int* fa, int ka, int lane) {
  const int* pa = fa + lane;
  for (;;) {
    int va;
    asm volatile("global_load_dword %0, %1, off sc1" : "=v"(va) : "v"(pa));
    asm volatile("s_waitcnt vmcnt(0)" : "+v"(va));
    if (__all(va >= ka)) return;
    __builtin_amdgcn_s_sleep(1);
  }
}
__device__ __forceinline__ void wait2(const int* fa, int ka, const int* fb, int kb, int lane) {
  const int* pa = fa + lane;
  const int* pb = fb + lane;
  for (;;) {
    int va, vb;
    asm volatile("global_load_dword %0, %1, off sc1" : "=v"(va) : "v"(pa));
    asm volatile("global_load_dword %0, %1, off sc1" : "=v"(vb) : "v"(pb));
    asm volatile("s_waitcnt vmcnt(0)" : "+v"(va), "+v"(vb));
    if (__all(va >= ka) && __all(vb >= kb)) return;
    __builtin_amdgcn_s_sleep(1);
  }
}
__device__ __forceinline__ void wait3(const int* fa, int ka, const int* fb, int kb,
                                      const int* fc, int kc, int lane) {
  const int* pa = fa + lane;
  const int* pb = fb + lane;
  const int* pc = fc + lane;
  for (;;) {
    int va, vb, vc;
    asm volatile("global_load_dword %0, %1, off sc1" : "=v"(va) : "v"(pa));
    asm volatile("global_load_dword %0, %1, off sc1" : "=v"(vb) : "v"(pb));
    asm volatile("global_load_dword %0, %1, off sc1" : "=v"(vc) : "v"(pc));
    asm volatile("s_waitcnt vmcnt(0)" : "+v"(va), "+v"(vb), "+v"(vc));
    if (__all(va >= ka) && __all(vb >= kb) && __all(vc >= kc)) return;
    __builtin_amdgcn_s_sleep(1);
  }
}

// ---------------- prep ----------------
__global__ void prep_kernel(const float* __restrict__ Whh0, const float* __restrict__ Wih1,
                            const float* __restrict__ Whh1, const float* __restrict__ Wih2,
                            const float* __restrict__ Whh2, const float* __restrict__ Wout,
                            const float* __restrict__ bih0, const float* __restrict__ bhh0,
                            const float* __restrict__ bih1, const float* __restrict__ bhh1,
                            const float* __restrict__ bih2, const float* __restrict__ bhh2,
                            const float* __restrict__ bout, void* wsv) {
  unsigned short* u = (unsigned short*)wsv;
  float* fr = (float*)((char*)wsv + FBYTE_BASE);
  int* fi = (int*)fr;
  size_t stride = (size_t)gridDim.x * blockDim.x;
  for (size_t i = (size_t)blockIdx.x * blockDim.x + threadIdx.x; i < PREP_TOTAL; i += stride) {
    if (i < 20971520UL) {
      size_t which = i >> 22;
      size_t off = i & (M4 - 1UL);
      const float* src = (which == 0) ? Whh0 : (which == 1) ? Wih1 :
                         (which == 2) ? Whh1 : (which == 3) ? Wih2 : Whh2;
      u[i] = f2bf(src[off]);
    } else if (i < 21102592UL) {
      size_t k = i - 20971520UL;
      size_t o = k >> 10, kk = k & 1023UL;
      u[i] = (o < 121) ? f2bf(Wout[o * 1024UL + kk]) : (unsigned short)0;
    } else if (i < 24248320UL) {
      u[i] = 0;                                   // zero all NS h slots x 3 layers
    } else if (i < 24444928UL) {
      fr[i - 24248320UL] = 0.0f;                  // zero c0,c1,c2
    } else if (i < 24457216UL) {
      size_t k = i - 24444928UL;
      size_t l = k >> 12, n = k & 4095UL;
      const float* bi = (l == 0) ? bih0 : (l == 1) ? bih1 : bih2;
      const float* bh = (l == 0) ? bhh0 : (l == 1) ? bhh1 : bhh2;
      fr[FOFF_B0 + l * 4096UL + n] = bi[n] + bh[n];
    } else if (i < 24457344UL) {
      size_t k = i - 24457216UL;
      fr[FOFF_BOUT + k] = (k < 121) ? bout[k] : 0.0f;
    } else {
      size_t k = i - 24457344UL;                  // 256 flags: 0..191 layers, 192..193 out
      fi[FOFF_FLAGS + k] = (k < 194UL) ? 0 : (1 << 29);
    }
  }
}

// ---------------- GEMM slice: register B, 6-deep explicit-vmcnt pipelined A ----------------
template <int NK>
__device__ __forceinline__ void gemm_bw(const unsigned short* __restrict__ arow,
                                        const short8 (&bw)[NK][4],
                                        f32x4 (&acc)[4][4]) {
  static_assert(NK >= 6, "pipeline depth");
  int4v ap[6][4];
#pragma unroll
  for (int g = 0; g < 6; ++g)
#pragma unroll
    for (int mt = 0; mt < 4; ++mt)
      gload16(ap[g][mt], arow + mt * 16 * HD + g * 32);
#pragma unroll
  for (int k = 0; k < NK; ++k) {
    const int s = k % 6;
    if (k <= NK - 6)          { AWAIT_N(20, ap[s][0], ap[s][1], ap[s][2], ap[s][3]); }
    else if (NK - 1 - k == 4) { AWAIT_N(16, ap[s][0], ap[s][1], ap[s][2], ap[s][3]); }
    else if (NK - 1 - k == 3) { AWAIT_N(12, ap[s][0], ap[s][1], ap[s][2], ap[s][3]); }
    else if (NK - 1 - k == 2) { AWAIT_N(8,  ap[s][0], ap[s][1], ap[s][2], ap[s][3]); }
    else if (NK - 1 - k == 1) { AWAIT_N(4,  ap[s][0], ap[s][1], ap[s][2], ap[s][3]); }
    else                      { AWAIT_N(0,  ap[s][0], ap[s][1], ap[s][2], ap[s][3]); }
#pragma unroll
    for (int mt = 0; mt < 4; ++mt) {
      short8 a = *(short8*)&ap[s][mt];
#pragma unroll
      for (int ns = 0; ns < 4; ++ns)
        acc[ns][mt] = __builtin_amdgcn_mfma_f32_16x16x32_bf16(a, bw[k][ns], acc[ns][mt], 0, 0, 0);
    }
    if (k + 6 < NK) {
#pragma unroll
      for (int mt = 0; mt < 4; ++mt)
        gload16(ap[s][mt], arow + mt * 16 * HD + (k + 6) * 32);
    }
  }
}

// ---------------- persistent-weight layer driver (dataflow-synced, cached A) ----------------
// RAW: own flags >= t (recurrence), producer flags >= t+1.
// WAR: NS=16-deep slots -> consumer flags >= t-15, folded into the main wait.
// Coherence: producer publishes with RELEASE store (waitcnt + buffer_wbl2 +
// sc1 flag store) => h is in MALL and valid in producer's L2 before flag is
// visible. Consumer acquire-fences once per NS steps (covers slot reuse in
// its own L1 + XCD L2); all other steps read fresh addresses -> no staleness.
template <bool L0L>
__device__ __forceinline__ void run_layer(
    int wgl, int tid,
    const unsigned short* __restrict__ hinbase,  // upstream h (NS slots), null for L0
    unsigned short* __restrict__ hbase,          // own h (NS slots)
    float* __restrict__ c,                       // [1024][64] fp32 transposed
    const unsigned short* __restrict__ Wih,      // null for L0
    const unsigned short* __restrict__ Whh,
    const float* __restrict__ bias,
    const float* __restrict__ strokes,           // L0 only
    const float* __restrict__ Wih0,              // L0 only, fp32 [4096][3]
    float* gbuf, int* fOwn, const int* fProd, const int* fCons) {
  constexpr int NK = L0L ? 8 : 16;
  const int lane = tid & 63;
  const int w = tid >> 6;
  const int nl = lane & 15;
  const int kq8 = (lane >> 4) << 3;

  const unsigned short* Wm;
  int k0beg;
  bool useHin;
  if (L0L) { Wm = Whh; k0beg = w * 256; useHin = false; }
  else     { Wm = (w < 2) ? Wih : Whh; k0beg = (w & 1) * 512; useHin = (w < 2); }

  short8 bw[NK][4];
#pragma unroll
  for (int ns = 0; ns < 4; ++ns) {
    int jgl = wgl * 16 + ns * 4 + (nl >> 2);
    int row = (nl & 3) * HD + jgl;                 // gate-major weight row
    const unsigned short* wr = Wm + (size_t)row * HD + kq8 + k0beg;
#pragma unroll
    for (int k = 0; k < NK; ++k) bw[k][ns] = *(const short8*)(wr + k * 32);
  }

  const int bb = (lane >> 4) << 2;
  float* gs = gbuf + w * 4096;

  for (int t = 0; t < TD; ++t) {
    // ---- RAW + WAR waits: wave 0 polls, others park at the barrier ----
    if (w == 0) {
      if (L0L) {
        if (t > 0) wait2(fOwn, t, fCons, t - (NS - 1), lane);
      } else {
        if (t > 0) wait3(fOwn, t, fProd, t + 1, fCons, t - (NS - 1), lane);
        else       wait1(fProd, 1, lane);
      }
    }
    __syncthreads();
    // Slot-reuse invalidate, once per NS steps (all waves: each wave's loads
    // are ordered after its own inv; L1 is per-CU, L2 per-XCD).
    if ((t & (NS - 1)) == 0) __builtin_amdgcn_fence(__ATOMIC_ACQUIRE, "agent");

    const unsigned short* A = useHin ? (hinbase + (size_t)(t & (NS - 1)) * BH)
                                     : (hbase + (size_t)((t - 1) & (NS - 1)) * BH);
    const unsigned short* arow = A + nl * HD + kq8 + k0beg;

    f32x4 acc[4][4];
    const f32x4 z4 = {0.f, 0.f, 0.f, 0.f};
#pragma unroll
    for (int ns = 0; ns < 4; ++ns)
#pragma unroll
      for (int mt = 0; mt < 4; ++mt) acc[ns][mt] = z4;

    gemm_bw<NK>(arow, bw, acc);

#pragma unroll
    for (int ns = 0; ns < 4; ++ns) {
      int gn = ns * 16 + nl;
#pragma unroll
      for (int mt = 0; mt < 4; ++mt)
#pragma unroll
        for (int r = 0; r < 4; ++r)
          gs[sw(gn, mt * 16 + bb + r)] = acc[ns][mt][r];
    }
    __syncthreads();

    unsigned short* hout = hbase + (size_t)(t & (NS - 1)) * BH;
#pragma unroll
    for (int it = 0; it < 2; ++it) {
      int item = it * 256 + tid;
      int jp = item >> 6;          // 0..7 pair of j
      int b = item & 63;
      unsigned hv[2];
#pragma unroll
      for (int u2 = 0; u2 < 2; ++u2) {
        int jj = jp * 2 + u2;
        int j = wgl * 16 + jj;
        float p[4];
#pragma unroll
        for (int g = 0; g < 4; ++g) {
          int a = sw(jj * 4 + g, b);
          p[g] = gbuf[a] + gbuf[4096 + a] + gbuf[8192 + a] + gbuf[12288 + a] + bias[g * HD + j];
        }
        if (L0L) {
          const float* xr = strokes + ((size_t)b * TD + t) * 3;
          float x0 = xr[0], x1 = xr[1], x2 = xr[2];
#pragma unroll
          for (int g = 0; g < 4; ++g) {
            const float* wr = Wih0 + (size_t)(g * HD + j) * 3;
            p[g] += x0 * wr[0] + x1 * wr[1] + x2 * wr[2];
          }
        }
        float iv = sigmoidf_(p[0]);
        float fv = sigmoidf_(p[1]);
        float gv = tanhf(p[2]);
        float ov = sigmoidf_(p[3]);
        int ci = j * BD + b;       // CU-private, normal cached RMW
        float cn = fv * c[ci] + iv * gv;
        c[ci] = cn;
        hv[u2] = (unsigned)f2bf(ov * tanhf(cn));
      }
      unsigned packed = hv[0] | (hv[1] << 16);
      *(unsigned*)(hout + (size_t)b * HD + wgl * 16 + jp * 2) = packed;  // plain cached store
    }
    // Per-wave: own h stores committed to L2. Then all waves synced, and the
    // RELEASE flag store (buffer_wbl2 + sc1) pushes everything to MALL before
    // the flag becomes visible to pollers.
    asm volatile("s_waitcnt vmcnt(0)" ::: "memory");
    __syncthreads();
    if (tid == 0)
      __hip_atomic_store(fOwn + wgl, t + 1, __ATOMIC_RELEASE, __HIP_MEMORY_SCOPE_AGENT);
  }
}

// ---------------- output projection driver (2 WGs x 64 o-columns) ----------------
__device__ __forceinline__ void run_out(
    int wgo, int tid,
    const unsigned short* __restrict__ h2base,
    const unsigned short* __restrict__ Wo,   // bf16 [128][1024] padded
    const float* __restrict__ bo,
    float* __restrict__ outp, float* gbuf, int* fOwn, const int* fProd) {
  const int lane = tid & 63;
  const int w = tid >> 6;
  const int nl = lane & 15;
  const int kq8 = (lane >> 4) << 3;
  const int k0beg = w * 256;

  short8 bw[8][4];
#pragma unroll
  for (int ns = 0; ns < 4; ++ns) {
    int o = wgo * 64 + ns * 16 + nl;
    const unsigned short* wr = Wo + (size_t)o * HD + kq8 + k0beg;
#pragma unroll
    for (int k = 0; k < 8; ++k) bw[k][ns] = *(const short8*)(wr + k * 32);
  }

  const int bb = (lane >> 4) << 2;
  float* gs = gbuf + w * 4096;

  for (int t = 0; t < TD; ++t) {
    if (w == 0) wait1(fProd, t + 1, lane);   // h2[t] published
    __syncthreads();
    if ((t & (NS - 1)) == 0) __builtin_amdgcn_fence(__ATOMIC_ACQUIRE, "agent");

    const unsigned short* arow = h2base + (size_t)(t & (NS - 1)) * BH + nl * HD + kq8 + k0beg;

    f32x4 acc[4][4];
    const f32x4 z4 = {0.f, 0.f, 0.f, 0.f};
#pragma unroll
    for (int ns = 0; ns < 4; ++ns)
#pragma unroll
      for (int mt = 0; mt < 4; ++mt) acc[ns][mt] = z4;

    gemm_bw<8>(arow, bw, acc);

#pragma unroll
    for (int ns = 0; ns < 4; ++ns) {
      int gn = ns * 16 + nl;
#pragma unroll
      for (int mt = 0; mt < 4; ++mt)
#pragma unroll
        for (int r = 0; r < 4; ++r)
          gs[sw(gn, mt * 16 + bb + r)] = acc[ns][mt][r];
    }
    __syncthreads();

#pragma unroll
    for (int it = 0; it < 16; ++it) {
      int item = it * 256 + tid;
      int ol = item >> 6;
      int b = item & 63;
      int o = wgo * 64 + ol;
      int a = sw(ol, b);
      float v = gbuf[a] + gbuf[4096 + a] + gbuf[8192 + a] + gbuf[12288 + a] + bo[o];
      if (o < 121) outp[((size_t)b * TD + t) * 121 + o] = v;
    }
    // A-reads of h2[t] fully retired (gemm drains to vmcnt 0) -> WAR signal
    // for layer2. Relaxed store: nothing of ours needs publishing.
    asm volatile("s_waitcnt vmcnt(0)" ::: "memory");
    __syncthreads();
    if (tid == 0)
      __hip_atomic_store(fOwn + wgo, t + 1, __ATOMIC_RELAXED, __HIP_MEMORY_SCOPE_AGENT);
  }
}

// ---------------- main kernel ----------------
// WGs 0..63 layer0, 64..127 layer1, 128..191 layer2, 192..193 out-proj.
// Plain launch; 194 blocks <= 256 CUs, co-resident (dataflow waits require it).
__global__ void __launch_bounds__(256, 1)
lstm_main(const float* __restrict__ strokes, const float* __restrict__ Wih0,
          float* __restrict__ outp, void* __restrict__ wsv) {
  __shared__ float gbuf[16384];  // 64 KB: 4 K-slices x [64 gn][64 b]
  unsigned short* u = (unsigned short*)wsv;
  float* fr = (float*)((char*)wsv + FBYTE_BASE);
  int* flags = (int*)fr + FOFF_FLAGS;
  int* f0 = flags;          // layer0 per-WG progress (64)
  int* f1 = flags + 64;     // layer1
  int* f2 = flags + 128;    // layer2
  int* f3 = flags + 192;    // out (2 real + 62 preset huge)

  const int wg = blockIdx.x;
  const int tid = threadIdx.x;

  if (wg < 64) {
    run_layer<true>(wg, tid, nullptr, u + OFF_H0, fr + FOFF_C0,
                    nullptr, u + OFF_WHH0, fr + FOFF_B0, strokes, Wih0, gbuf,
                    f0, nullptr, f1);
  } else if (wg < 128) {
    run_layer<false>(wg - 64, tid, u + OFF_H0, u + OFF_H1, fr + FOFF_C1,
                     u + OFF_WIH1, u + OFF_WHH1, fr + FOFF_B1, nullptr, nullptr, gbuf,
                     f1, f0, f2);
  } else if (wg < 192) {
    run_layer<false>(wg - 128, tid, u + OFF_H1, u + OFF_H2, fr + FOFF_C2,
                     u + OFF_WIH2, u + OFF_WHH2, fr + FOFF_B2, nullptr, nullptr, gbuf,
                     f2, f1, f3);
  } else {
    run_out(wg - 192, tid, u + OFF_H2, u + OFF_WOUT, fr + FOFF_BOUT, outp, gbuf,
            f3, f2);
  }
}

extern "C" void kernel_launch(void* const* d_in, const int* in_sizes, int n_in,
                              void* d_out, int out_size, void* d_ws, size_t ws_size,
                              hipStream_t stream) {
  const float* strokes = (const float*)d_in[0];
  const float* Wih0 = (const float*)d_in[1];
  const float* Whh0 = (const float*)d_in[2];
  const float* bih0 = (const float*)d_in[3];
  const float* bhh0 = (const float*)d_in[4];
  const float* Wih1 = (const float*)d_in[5];
  const float* Whh1 = (const float*)d_in[6];
  const float* bih1 = (const float*)d_in[7];
  const float* bhh1 = (const float*)d_in[8];
  const float* Wih2 = (const float*)d_in[9];
  const float* Whh2 = (const float*)d_in[10];
  const float* bih2 = (const float*)d_in[11];
  const float* bhh2 = (const float*)d_in[12];
  const float* Wout = (const float*)d_in[13];
  const float* bout = (const float*)d_in[14];
  float* outp = (float*)d_out;

  hipLaunchKernelGGL(prep_kernel, dim3(4096), dim3(256), 0, stream,
                     Whh0, Wih1, Whh1, Wih2, Whh2, Wout,
                     bih0, bhh0, bih1, bhh1, bih2, bhh2, bout, d_ws);

  hipLaunchKernelGGL(lstm_main, dim3(NBLK), dim3(256), 0, stream,
                     strokes, Wih0, outp, d_ws);
}

// Round 4
// 8894.454 us; speedup vs baseline: 1.3292x; 1.2508x over previous
//
#include <hip/hip_runtime.h>

typedef __attribute__((ext_vector_type(8))) short short8;
typedef __attribute__((ext_vector_type(4))) float f32x4;
typedef __attribute__((ext_vector_type(4))) int int4v;

#define HD 1024
#define BD 64
#define TD 512
#define BH 65536UL  // one h slot: 64*1024 ushorts (128 KB)
#define NS 16       // h slot rotation depth == fence period
#define NBLK 194

// ---------------- workspace layout ----------------
#define M4 4194304UL
#define OFF_WHH0 0UL
#define OFF_WIH1 (1UL * M4)
#define OFF_WHH1 (2UL * M4)
#define OFF_WIH2 (3UL * M4)
#define OFF_WHH2 (4UL * M4)
#define OFF_WOUT (5UL * M4)                 // 128 x 1024 (padded rows zeroed)
#define OFF_H0   (OFF_WOUT + 131072UL)      // [NS slots][64][1024] per layer
#define OFF_H1   (OFF_H0 + (NS * BH))
#define OFF_H2   (OFF_H1 + (NS * BH))
#define USHORT_TOTAL (OFF_H2 + (NS * BH))   // 24248320
#define FBYTE_BASE (USHORT_TOTAL * 2UL)
#define FOFF_C0 0UL                          // c stored [j][b] (transposed)
#define FOFF_C1 65536UL
#define FOFF_C2 131072UL
#define FOFF_B0 196608UL                     // combined biases b_ih+b_hh [4096]
#define FOFF_B1 200704UL
#define FOFF_B2 204800UL
#define FOFF_BOUT 208896UL                   // [128], pad zeroed
#define FOFF_FLAGS 209024UL                  // int-indexed: 4 arrays x 64 per-WG flags
#define PREP_TOTAL 24457600UL

__device__ __forceinline__ unsigned short f2bf(float f) {
  union { float f; unsigned u; } v; v.f = f;
  unsigned r = v.u + 0x7fffu + ((v.u >> 16) & 1u);  // RNE
  return (unsigned short)(r >> 16);
}
__device__ __forceinline__ float sigmoidf_(float x) {
  return 1.0f / (1.0f + __expf(-x));
}
// LDS bank swizzle (unchanged).
__device__ __forceinline__ int sw(int gn, int b) {
  return gn * 64 + (b ^ (((gn & 7) << 2) | ((gn >> 3) & 3)));
}

// A-matrix load: plain cached 16B load. Coherence contract (each element
// HW-validated in a prior passing round):
//  - producers store h via sc1 write-through (R0/R1) and drain vmcnt(0)
//    BEFORE the relaxed flag store -> MALL is fresh when the flag flips.
//  - h slot addresses rotate NS=16 deep; a consumer cache can only hold a
//    stale copy of an address whose last read was >=16 steps ago, and a
//    per-16-step acquire fence (R2/R3) invalidates those. Between that
//    fence and the producer's store, NO wave reads the address (slot t&15
//    is only read at steps t and t+1, both flag-gated after the store),
//    so no stale refill can occur.
__device__ __forceinline__ void gload16(int4v& dst, const unsigned short* p) {
  asm volatile("global_load_dwordx4 %0, %1, off" : "=v"(dst) : "v"(p));
}
#define AWAIT_N(N, a0, a1, a2, a3) \
  asm volatile("s_waitcnt vmcnt(" #N ")" : "+v"(a0), "+v"(a1), "+v"(a2), "+v"(a3))

// ---------------- per-WG progress flags ----------------
// One int per WG, 64 per array (out array: 2 real + 62 preset huge).
// Per-WAVE decoupled waits: each wave polls only the flags its own A-loads
// depend on (lane i reads flag i, 4B sc1). Signal: ONE relaxed sc1 store
// per WG after all waves drained their h stores (no RMW, no release/wbl2).
__device__ __forceinline__ void wait1(const int* fa, int ka, int lane) {
  const int* pa = fa + lane;
  for (;;) {
    int va;
    asm volatile("global_load_dword %0, %1, off sc1" : "=v"(va) : "v"(pa));
    asm volatile("s_waitcnt vmcnt(0)" : "+v"(va));
    if (__all(va >= ka)) return;
    __builtin_amdgcn_s_sleep(1);
  }
}
__device__ __forceinline__ void wait2(const int* fa, int ka, const int* fb, int kb, int lane) {
  const int* pa = fa + lane;
  const int* pb = fb + lane;
  for (;;) {
    int va, vb;
    asm volatile("global_load_dword %0, %1, off sc1" : "=v"(va) : "v"(pa));
    asm volatile("global_load_dword %0, %1, off sc1" : "=v"(vb) : "v"(pb));
    asm volatile("s_waitcnt vmcnt(0)" : "+v"(va), "+v"(vb));
    if (__all(va >= ka) && __all(vb >= kb)) return;
    __builtin_amdgcn_s_sleep(1);
  }
}

// ---------------- prep ----------------
__global__ void prep_kernel(const float* __restrict__ Whh0, const float* __restrict__ Wih1,
                            const float* __restrict__ Whh1, const float* __restrict__ Wih2,
                            const float* __restrict__ Whh2, const float* __restrict__ Wout,
                            const float* __restrict__ bih0, const float* __restrict__ bhh0,
                            const float* __restrict__ bih1, const float* __restrict__ bhh1,
                            const float* __restrict__ bih2, const float* __restrict__ bhh2,
                            const float* __restrict__ bout, void* wsv) {
  unsigned short* u = (unsigned short*)wsv;
  float* fr = (float*)((char*)wsv + FBYTE_BASE);
  int* fi = (int*)fr;
  size_t stride = (size_t)gridDim.x * blockDim.x;
  for (size_t i = (size_t)blockIdx.x * blockDim.x + threadIdx.x; i < PREP_TOTAL; i += stride) {
    if (i < 20971520UL) {
      size_t which = i >> 22;
      size_t off = i & (M4 - 1UL);
      const float* src = (which == 0) ? Whh0 : (which == 1) ? Wih1 :
                         (which == 2) ? Whh1 : (which == 3) ? Wih2 : Whh2;
      u[i] = f2bf(src[off]);
    } else if (i < 21102592UL) {
      size_t k = i - 20971520UL;
      size_t o = k >> 10, kk = k & 1023UL;
      u[i] = (o < 121) ? f2bf(Wout[o * 1024UL + kk]) : (unsigned short)0;
    } else if (i < 24248320UL) {
      u[i] = 0;                                   // zero all NS h slots x 3 layers
    } else if (i < 24444928UL) {
      fr[i - 24248320UL] = 0.0f;                  // zero c0,c1,c2
    } else if (i < 24457216UL) {
      size_t k = i - 24444928UL;
      size_t l = k >> 12, n = k & 4095UL;
      const float* bi = (l == 0) ? bih0 : (l == 1) ? bih1 : bih2;
      const float* bh = (l == 0) ? bhh0 : (l == 1) ? bhh1 : bhh2;
      fr[FOFF_B0 + l * 4096UL + n] = bi[n] + bh[n];
    } else if (i < 24457344UL) {
      size_t k = i - 24457216UL;
      fr[FOFF_BOUT + k] = (k < 121) ? bout[k] : 0.0f;
    } else {
      size_t k = i - 24457344UL;                  // 256 flags: 0..191 layers, 192..193 out
      fi[FOFF_FLAGS + k] = (k < 194UL) ? 0 : (1 << 29);
    }
  }
}

// ---------------- GEMM slice: register B, 6-deep explicit-vmcnt pipelined A ----------------
template <int NK>
__device__ __forceinline__ void gemm_bw(const unsigned short* __restrict__ arow,
                                        const short8 (&bw)[NK][4],
                                        f32x4 (&acc)[4][4]) {
  static_assert(NK >= 6, "pipeline depth");
  int4v ap[6][4];
#pragma unroll
  for (int g = 0; g < 6; ++g)
#pragma unroll
    for (int mt = 0; mt < 4; ++mt)
      gload16(ap[g][mt], arow + mt * 16 * HD + g * 32);
#pragma unroll
  for (int k = 0; k < NK; ++k) {
    const int s = k % 6;
    if (k <= NK - 6)          { AWAIT_N(20, ap[s][0], ap[s][1], ap[s][2], ap[s][3]); }
    else if (NK - 1 - k == 4) { AWAIT_N(16, ap[s][0], ap[s][1], ap[s][2], ap[s][3]); }
    else if (NK - 1 - k == 3) { AWAIT_N(12, ap[s][0], ap[s][1], ap[s][2], ap[s][3]); }
    else if (NK - 1 - k == 2) { AWAIT_N(8,  ap[s][0], ap[s][1], ap[s][2], ap[s][3]); }
    else if (NK - 1 - k == 1) { AWAIT_N(4,  ap[s][0], ap[s][1], ap[s][2], ap[s][3]); }
    else                      { AWAIT_N(0,  ap[s][0], ap[s][1], ap[s][2], ap[s][3]); }
#pragma unroll
    for (int mt = 0; mt < 4; ++mt) {
      short8 a = *(short8*)&ap[s][mt];
#pragma unroll
      for (int ns = 0; ns < 4; ++ns)
        acc[ns][mt] = __builtin_amdgcn_mfma_f32_16x16x32_bf16(a, bw[k][ns], acc[ns][mt], 0, 0, 0);
    }
    if (k + 6 < NK) {
#pragma unroll
      for (int mt = 0; mt < 4; ++mt)
        gload16(ap[s][mt], arow + mt * 16 * HD + (k + 6) * 32);
    }
  }
}

// ---------------- persistent-weight layer driver (dataflow-synced, cached A) ----------------
// Per-wave decoupled waits:
//   w0/w1 (hin waves, non-L0): fProd >= t+1 only -- producer runs a step
//     ahead, so these waves start their 128 KB of loads immediately.
//   w2/w3 (recurrence waves): fOwn >= t -- the only latency-critical edge.
//   w0 additionally carries the WAR bound (fCons >= t-15, NS-deep slots),
//   which is enforced before h-stores by the mid __syncthreads.
template <bool L0L>
__device__ __forceinline__ void run_layer(
    int wgl, int tid,
    const unsigned short* __restrict__ hinbase,  // upstream h (NS slots), null for L0
    unsigned short* __restrict__ hbase,          // own h (NS slots)
    float* __restrict__ c,                       // [1024][64] fp32 transposed
    const unsigned short* __restrict__ Wih,      // null for L0
    const unsigned short* __restrict__ Whh,
    const float* __restrict__ bias,
    const float* __restrict__ strokes,           // L0 only
    const float* __restrict__ Wih0,              // L0 only, fp32 [4096][3]
    float* gbuf, int* fOwn, const int* fProd, const int* fCons) {
  constexpr int NK = L0L ? 8 : 16;
  const int lane = tid & 63;
  const int w = tid >> 6;
  const int nl = lane & 15;
  const int kq8 = (lane >> 4) << 3;

  const unsigned short* Wm;
  int k0beg;
  bool useHin;
  if (L0L) { Wm = Whh; k0beg = w * 256; useHin = false; }
  else     { Wm = (w < 2) ? Wih : Whh; k0beg = (w & 1) * 512; useHin = (w < 2); }

  short8 bw[NK][4];
#pragma unroll
  for (int ns = 0; ns < 4; ++ns) {
    int jgl = wgl * 16 + ns * 4 + (nl >> 2);
    int row = (nl & 3) * HD + jgl;                 // gate-major weight row
    const unsigned short* wr = Wm + (size_t)row * HD + kq8 + k0beg;
#pragma unroll
    for (int k = 0; k < NK; ++k) bw[k][ns] = *(const short8*)(wr + k * 32);
  }

  const int bb = (lane >> 4) << 2;
  float* gs = gbuf + w * 4096;

  for (int t = 0; t < TD; ++t) {
    // ---- per-wave decoupled RAW waits (+ WAR bound on w0) ----
    if (L0L) {
      if (t > 0) {
        if (w == 0) wait2(fOwn, t, fCons, t - (NS - 1), lane);
        else        wait1(fOwn, t, lane);
      }
    } else {
      if (useHin) {             // w0/w1: upstream data, typically ready
        if (w == 0) {
          if (t > 0) wait2(fProd, t + 1, fCons, t - (NS - 1), lane);
          else       wait1(fProd, 1, lane);
        } else {
          wait1(fProd, t + 1, lane);
        }
      } else {                  // w2/w3: recurrence-critical
        if (t > 0) wait1(fOwn, t, lane);
      }
    }
    // Slot-reuse invalidate, once per NS steps (cheap: 1/16 of steps).
    if ((t & (NS - 1)) == 0) __builtin_amdgcn_fence(__ATOMIC_ACQUIRE, "agent");

    const unsigned short* A = useHin ? (hinbase + (size_t)(t & (NS - 1)) * BH)
                                     : (hbase + (size_t)((t - 1) & (NS - 1)) * BH);
    const unsigned short* arow = A + nl * HD + kq8 + k0beg;

    f32x4 acc[4][4];
    const f32x4 z4 = {0.f, 0.f, 0.f, 0.f};
#pragma unroll
    for (int ns = 0; ns < 4; ++ns)
#pragma unroll
      for (int mt = 0; mt < 4; ++mt) acc[ns][mt] = z4;

    gemm_bw<NK>(arow, bw, acc);

#pragma unroll
    for (int ns = 0; ns < 4; ++ns) {
      int gn = ns * 16 + nl;
#pragma unroll
      for (int mt = 0; mt < 4; ++mt)
#pragma unroll
        for (int r = 0; r < 4; ++r)
          gs[sw(gn, mt * 16 + bb + r)] = acc[ns][mt][r];
    }
    __syncthreads();  // gbuf ready; also orders h-stores after w0's WAR check

    unsigned short* hout = hbase + (size_t)(t & (NS - 1)) * BH;
#pragma unroll
    for (int it = 0; it < 2; ++it) {
      int item = it * 256 + tid;
      int jp = item >> 6;          // 0..7 pair of j
      int b = item & 63;
      unsigned hv[2];
#pragma unroll
      for (int u2 = 0; u2 < 2; ++u2) {
        int jj = jp * 2 + u2;
        int j = wgl * 16 + jj;
        float p[4];
#pragma unroll
        for (int g = 0; g < 4; ++g) {
          int a = sw(jj * 4 + g, b);
          p[g] = gbuf[a] + gbuf[4096 + a] + gbuf[8192 + a] + gbuf[12288 + a] + bias[g * HD + j];
        }
        if (L0L) {
          const float* xr = strokes + ((size_t)b * TD + t) * 3;
          float x0 = xr[0], x1 = xr[1], x2 = xr[2];
#pragma unroll
          for (int g = 0; g < 4; ++g) {
            const float* wr = Wih0 + (size_t)(g * HD + j) * 3;
            p[g] += x0 * wr[0] + x1 * wr[1] + x2 * wr[2];
          }
        }
        float iv = sigmoidf_(p[0]);
        float fv = sigmoidf_(p[1]);
        float gv = tanhf(p[2]);
        float ov = sigmoidf_(p[3]);
        int ci = j * BD + b;       // CU-private, normal cached RMW
        float cn = fv * c[ci] + iv * gv;
        c[ci] = cn;
        hv[u2] = (unsigned)f2bf(ov * tanhf(cn));
      }
      unsigned packed = hv[0] | (hv[1] << 16);
      // sc1 write-through: MALL is the coherence point consumers fetch from.
      __hip_atomic_store((unsigned*)(hout + (size_t)b * HD + wgl * 16 + jp * 2), packed,
                         __ATOMIC_RELAXED, __HIP_MEMORY_SCOPE_AGENT);
    }
    // Drain own h stores to MALL, sync all waves, then publish (relaxed --
    // NO release/wbl2: the sc1 stores are already at the coherence point).
    asm volatile("s_waitcnt vmcnt(0)" ::: "memory");
    __syncthreads();
    if (tid == 0)
      __hip_atomic_store(fOwn + wgl, t + 1, __ATOMIC_RELAXED, __HIP_MEMORY_SCOPE_AGENT);
  }
}

// ---------------- output projection driver (2 WGs x 64 o-columns) ----------------
__device__ __forceinline__ void run_out(
    int wgo, int tid,
    const unsigned short* __restrict__ h2base,
    const unsigned short* __restrict__ Wo,   // bf16 [128][1024] padded
    const float* __restrict__ bo,
    float* __restrict__ outp, float* gbuf, int* fOwn, const int* fProd) {
  const int lane = tid & 63;
  const int w = tid >> 6;
  const int nl = lane & 15;
  const int kq8 = (lane >> 4) << 3;
  const int k0beg = w * 256;

  short8 bw[8][4];
#pragma unroll
  for (int ns = 0; ns < 4; ++ns) {
    int o = wgo * 64 + ns * 16 + nl;
    const unsigned short* wr = Wo + (size_t)o * HD + kq8 + k0beg;
#pragma unroll
    for (int k = 0; k < 8; ++k) bw[k][ns] = *(const short8*)(wr + k * 32);
  }

  const int bb = (lane >> 4) << 2;
  float* gs = gbuf + w * 4096;

  for (int t = 0; t < TD; ++t) {
    wait1(fProd, t + 1, lane);   // every wave polls independently
    if ((t & (NS - 1)) == 0) __builtin_amdgcn_fence(__ATOMIC_ACQUIRE, "agent");

    const unsigned short* arow = h2base + (size_t)(t & (NS - 1)) * BH + nl * HD + kq8 + k0beg;

    f32x4 acc[4][4];
    const f32x4 z4 = {0.f, 0.f, 0.f, 0.f};
#pragma unroll
    for (int ns = 0; ns < 4; ++ns)
#pragma unroll
      for (int mt = 0; mt < 4; ++mt) acc[ns][mt] = z4;

    gemm_bw<8>(arow, bw, acc);

#pragma unroll
    for (int ns = 0; ns < 4; ++ns) {
      int gn = ns * 16 + nl;
#pragma unroll
      for (int mt = 0; mt < 4; ++mt)
#pragma unroll
        for (int r = 0; r < 4; ++r)
          gs[sw(gn, mt * 16 + bb + r)] = acc[ns][mt][r];
    }
    __syncthreads();

#pragma unroll
    for (int it = 0; it < 16; ++it) {
      int item = it * 256 + tid;
      int ol = item >> 6;
      int b = item & 63;
      int o = wgo * 64 + ol;
      int a = sw(ol, b);
      float v = gbuf[a] + gbuf[4096 + a] + gbuf[8192 + a] + gbuf[12288 + a] + bo[o];
      if (o < 121) outp[((size_t)b * TD + t) * 121 + o] = v;
    }
    // A-reads of h2[t] fully retired (gemm drains to vmcnt 0) -> WAR signal
    // for layer2.
    asm volatile("s_waitcnt vmcnt(0)" ::: "memory");
    __syncthreads();
    if (tid == 0)
      __hip_atomic_store(fOwn + wgo, t + 1, __ATOMIC_RELAXED, __HIP_MEMORY_SCOPE_AGENT);
  }
}

// ---------------- main kernel ----------------
// WGs 0..63 layer0, 64..127 layer1, 128..191 layer2, 192..193 out-proj.
// Plain launch; 194 blocks <= 256 CUs, co-resident (dataflow waits require it).
__global__ void __launch_bounds__(256, 1)
lstm_main(const float* __restrict__ strokes, const float* __restrict__ Wih0,
          float* __restrict__ outp, void* __restrict__ wsv) {
  __shared__ float gbuf[16384];  // 64 KB: 4 K-slices x [64 gn][64 b]
  unsigned short* u = (unsigned short*)wsv;
  float* fr = (float*)((char*)wsv + FBYTE_BASE);
  int* flags = (int*)fr + FOFF_FLAGS;
  int* f0 = flags;          // layer0 per-WG progress (64)
  int* f1 = flags + 64;     // layer1
  int* f2 = flags + 128;    // layer2
  int* f3 = flags + 192;    // out (2 real + 62 preset huge)

  const int wg = blockIdx.x;
  const int tid = threadIdx.x;

  if (wg < 64) {
    run_layer<true>(wg, tid, nullptr, u + OFF_H0, fr + FOFF_C0,
                    nullptr, u + OFF_WHH0, fr + FOFF_B0, strokes, Wih0, gbuf,
                    f0, nullptr, f1);
  } else if (wg < 128) {
    run_layer<false>(wg - 64, tid, u + OFF_H0, u + OFF_H1, fr + FOFF_C1,
                     u + OFF_WIH1, u + OFF_WHH1, fr + FOFF_B1, nullptr, nullptr, gbuf,
                     f1, f0, f2);
  } else if (wg < 192) {
    run_layer<false>(wg - 128, tid, u + OFF_H1, u + OFF_H2, fr + FOFF_C2,
                     u + OFF_WIH2, u + OFF_WHH2, fr + FOFF_B2, nullptr, nullptr, gbuf,
                     f2, f1, f3);
  } else {
    run_out(wg - 192, tid, u + OFF_H2, u + OFF_WOUT, fr + FOFF_BOUT, outp, gbuf,
            f3, f2);
  }
}

extern "C" void kernel_launch(void* const* d_in, const int* in_sizes, int n_in,
                              void* d_out, int out_size, void* d_ws, size_t ws_size,
                              hipStream_t stream) {
  const float* strokes = (const float*)d_in[0];
  const float* Wih0 = (const float*)d_in[1];
  const float* Whh0 = (const float*)d_in[2];
  const float* bih0 = (const float*)d_in[3];
  const float* bhh0 = (const float*)d_in[4];
  const float* Wih1 = (const float*)d_in[5];
  const float* Whh1 = (const float*)d_in[6];
  const float* bih1 = (const float*)d_in[7];
  const float* bhh1 = (const float*)d_in[8];
  const float* Wih2 = (const float*)d_in[9];
  const float* Whh2 = (const float*)d_in[10];
  const float* bih2 = (const float*)d_in[11];
  const float* bhh2 = (const float*)d_in[12];
  const float* Wout = (const float*)d_in[13];
  const float* bout = (const float*)d_in[14];
  float* outp = (float*)d_out;

  hipLaunchKernelGGL(prep_kernel, dim3(4096), dim3(256), 0, stream,
                     Whh0, Wih1, Whh1, Wih2, Whh2, Wout,
                     bih0, bhh0, bih1, bhh1, bih2, bhh2, bout, d_ws);

  hipLaunchKernelGGL(lstm_main, dim3(NBLK), dim3(256), 0, stream,
                     strokes, Wih0, outp, d_ws);
}

// Round 5
// 8823.312 us; speedup vs baseline: 1.3400x; 1.0081x over previous
//
#include <hip/hip_runtime.h>

typedef __attribute__((ext_vector_type(8))) short short8;
typedef __attribute__((ext_vector_type(4))) float f32x4;
typedef __attribute__((ext_vector_type(4))) int int4v;

#define HD 1024
#define BD 64
#define TD 512
#define BH 65536UL  // one h slot: 64*1024 ushorts (128 KB)
#define NS 16       // h slot rotation depth == fence period
#define NBLK 256    // 1 block/CU; XCD-partitioned mapping inside

// ---------------- workspace layout ----------------
#define M4 4194304UL
#define OFF_WHH0 0UL
#define OFF_WIH1 (1UL * M4)
#define OFF_WHH1 (2UL * M4)
#define OFF_WIH2 (3UL * M4)
#define OFF_WHH2 (4UL * M4)
#define OFF_WOUT (5UL * M4)                 // 128 x 1024 (padded rows zeroed)
#define OFF_H0   (OFF_WOUT + 131072UL)      // [NS slots][64][1024] per layer
#define OFF_H1   (OFF_H0 + (NS * BH))
#define OFF_H2   (OFF_H1 + (NS * BH))
#define USHORT_TOTAL (OFF_H2 + (NS * BH))   // 24248320
#define FBYTE_BASE (USHORT_TOTAL * 2UL)
#define FOFF_C0 0UL                          // c stored [j][b] (transposed)
#define FOFF_C1 65536UL
#define FOFF_C2 131072UL
#define FOFF_B0 196608UL                     // combined biases b_ih+b_hh [4096]
#define FOFF_B1 200704UL
#define FOFF_B2 204800UL
#define FOFF_BOUT 208896UL                   // [128], pad zeroed
#define FOFF_FLAGS 209024UL                  // int-indexed: 4 arrays x 64 per-WG flags
#define PREP_TOTAL 24457600UL

__device__ __forceinline__ unsigned short f2bf(float f) {
  union { float f; unsigned u; } v; v.f = f;
  unsigned r = v.u + 0x7fffu + ((v.u >> 16) & 1u);  // RNE
  return (unsigned short)(r >> 16);
}
__device__ __forceinline__ float sigmoidf_(float x) {
  return 1.0f / (1.0f + __expf(-x));
}
// LDS bank swizzle (unchanged).
__device__ __forceinline__ int sw(int gn, int b) {
  return gn * 64 + (b ^ (((gn & 7) << 2) | ((gn >> 3) & 3)));
}

// A-matrix load: plain cached 16B load. With the XCD-partitioned layout all
// 32 WGs of a layer-half share one L2 and read the SAME 256 KB per step, so
// after the first toucher pulls a line from MALL the rest hit L2 (~300 cy).
// Coherence contract (HW-validated R4): producers sc1-write-through h and
// drain vmcnt(0) before the relaxed flag store; NS=16 slot rotation + one
// acquire fence per 16-step window guarantees no stale L2/L1 line can serve
// a current-slot read (per-address proof independent of sharer count).
__device__ __forceinline__ void gload16(int4v& dst, const unsigned short* p) {
  asm volatile("global_load_dwordx4 %0, %1, off" : "=v"(dst) : "v"(p));
}
#define AWAIT_N(N, a0, a1, a2, a3) \
  asm volatile("s_waitcnt vmcnt(" #N ")" : "+v"(a0), "+v"(a1), "+v"(a2), "+v"(a3))

// ---------------- per-WG progress flags ----------------
// One int per WG, 64 per array (out array: 2 real + 62 preset huge).
// Per-WAVE decoupled waits: each wave polls only the flags its own A-loads
// depend on (lane i reads flag i, 4B sc1). Signal: ONE relaxed sc1 store
// per WG after all waves drained their h stores (no RMW, no release/wbl2).
__device__ __forceinline__ void wait1(const int* fa, int ka, int lane) {
  const int* pa = fa + lane;
  for (;;) {
    int va;
    asm volatile("global_load_dword %0, %1, off sc1" : "=v"(va) : "v"(pa));
    asm volatile("s_waitcnt vmcnt(0)" : "+v"(va));
    if (__all(va >= ka)) return;
    __builtin_amdgcn_s_sleep(1);
  }
}
__device__ __forceinline__ void wait2(const int* fa, int ka, const int* fb, int kb, int lane) {
  const int* pa = fa + lane;
  const int* pb = fb + lane;
  for (;;) {
    int va, vb;
    asm volatile("global_load_dword %0, %1, off sc1" : "=v"(va) : "v"(pa));
    asm volatile("global_load_dword %0, %1, off sc1" : "=v"(vb) : "v"(pb));
    asm volatile("s_waitcnt vmcnt(0)" : "+v"(va), "+v"(vb));
    if (__all(va >= ka) && __all(vb >= kb)) return;
    __builtin_amdgcn_s_sleep(1);
  }
}

// ---------------- prep ----------------
__global__ void prep_kernel(const float* __restrict__ Whh0, const float* __restrict__ Wih1,
                            const float* __restrict__ Whh1, const float* __restrict__ Wih2,
                            const float* __restrict__ Whh2, const float* __restrict__ Wout,
                            const float* __restrict__ bih0, const float* __restrict__ bhh0,
                            const float* __restrict__ bih1, const float* __restrict__ bhh1,
                            const float* __restrict__ bih2, const float* __restrict__ bhh2,
                            const float* __restrict__ bout, void* wsv) {
  unsigned short* u = (unsigned short*)wsv;
  float* fr = (float*)((char*)wsv + FBYTE_BASE);
  int* fi = (int*)fr;
  size_t stride = (size_t)gridDim.x * blockDim.x;
  for (size_t i = (size_t)blockIdx.x * blockDim.x + threadIdx.x; i < PREP_TOTAL; i += stride) {
    if (i < 20971520UL) {
      size_t which = i >> 22;
      size_t off = i & (M4 - 1UL);
      const float* src = (which == 0) ? Whh0 : (which == 1) ? Wih1 :
                         (which == 2) ? Whh1 : (which == 3) ? Wih2 : Whh2;
      u[i] = f2bf(src[off]);
    } else if (i < 21102592UL) {
      size_t k = i - 20971520UL;
      size_t o = k >> 10, kk = k & 1023UL;
      u[i] = (o < 121) ? f2bf(Wout[o * 1024UL + kk]) : (unsigned short)0;
    } else if (i < 24248320UL) {
      u[i] = 0;                                   // zero all NS h slots x 3 layers
    } else if (i < 24444928UL) {
      fr[i - 24248320UL] = 0.0f;                  // zero c0,c1,c2
    } else if (i < 24457216UL) {
      size_t k = i - 24444928UL;
      size_t l = k >> 12, n = k & 4095UL;
      const float* bi = (l == 0) ? bih0 : (l == 1) ? bih1 : bih2;
      const float* bh = (l == 0) ? bhh0 : (l == 1) ? bhh1 : bhh2;
      fr[FOFF_B0 + l * 4096UL + n] = bi[n] + bh[n];
    } else if (i < 24457344UL) {
      size_t k = i - 24457216UL;
      fr[FOFF_BOUT + k] = (k < 121) ? bout[k] : 0.0f;
    } else {
      size_t k = i - 24457344UL;                  // 256 flags: 0..191 layers, 192..193 out
      fi[FOFF_FLAGS + k] = (k < 194UL) ? 0 : (1 << 29);
    }
  }
}

// ---------------- GEMM slice: register B, 6-deep explicit-vmcnt pipelined A ----------------
template <int NK>
__device__ __forceinline__ void gemm_bw(const unsigned short* __restrict__ arow,
                                        const short8 (&bw)[NK][4],
                                        f32x4 (&acc)[4][4]) {
  static_assert(NK >= 6, "pipeline depth");
  int4v ap[6][4];
#pragma unroll
  for (int g = 0; g < 6; ++g)
#pragma unroll
    for (int mt = 0; mt < 4; ++mt)
      gload16(ap[g][mt], arow + mt * 16 * HD + g * 32);
#pragma unroll
  for (int k = 0; k < NK; ++k) {
    const int s = k % 6;
    if (k <= NK - 6)          { AWAIT_N(20, ap[s][0], ap[s][1], ap[s][2], ap[s][3]); }
    else if (NK - 1 - k == 4) { AWAIT_N(16, ap[s][0], ap[s][1], ap[s][2], ap[s][3]); }
    else if (NK - 1 - k == 3) { AWAIT_N(12, ap[s][0], ap[s][1], ap[s][2], ap[s][3]); }
    else if (NK - 1 - k == 2) { AWAIT_N(8,  ap[s][0], ap[s][1], ap[s][2], ap[s][3]); }
    else if (NK - 1 - k == 1) { AWAIT_N(4,  ap[s][0], ap[s][1], ap[s][2], ap[s][3]); }
    else                      { AWAIT_N(0,  ap[s][0], ap[s][1], ap[s][2], ap[s][3]); }
#pragma unroll
    for (int mt = 0; mt < 4; ++mt) {
      short8 a = *(short8*)&ap[s][mt];
#pragma unroll
      for (int ns = 0; ns < 4; ++ns)
        acc[ns][mt] = __builtin_amdgcn_mfma_f32_16x16x32_bf16(a, bw[k][ns], acc[ns][mt], 0, 0, 0);
    }
    if (k + 6 < NK) {
#pragma unroll
      for (int mt = 0; mt < 4; ++mt)
        gload16(ap[s][mt], arow + mt * 16 * HD + (k + 6) * 32);
    }
  }
}

// ---------------- persistent-weight layer driver (dataflow-synced, cached A) ----------------
// Per-wave decoupled waits:
//   w0/w1 (hin waves, non-L0): fProd >= t+1 only -- producer runs a step
//     ahead, so these waves start their 128 KB of loads immediately.
//   w2/w3 (recurrence waves): fOwn >= t -- the only latency-critical edge.
//   w0 additionally carries the WAR bound (fCons >= t-15, NS-deep slots),
//   which is enforced before h-stores by the mid __syncthreads.
template <bool L0L>
__device__ __forceinline__ void run_layer(
    int wgl, int tid,
    const unsigned short* __restrict__ hinbase,  // upstream h (NS slots), null for L0
    unsigned short* __restrict__ hbase,          // own h (NS slots)
    float* __restrict__ c,                       // [1024][64] fp32 transposed
    const unsigned short* __restrict__ Wih,      // null for L0
    const unsigned short* __restrict__ Whh,
    const float* __restrict__ bias,
    const float* __restrict__ strokes,           // L0 only
    const float* __restrict__ Wih0,              // L0 only, fp32 [4096][3]
    float* gbuf, int* fOwn, const int* fProd, const int* fCons) {
  constexpr int NK = L0L ? 8 : 16;
  const int lane = tid & 63;
  const int w = tid >> 6;
  const int nl = lane & 15;
  const int kq8 = (lane >> 4) << 3;

  const unsigned short* Wm;
  int k0beg;
  bool useHin;
  if (L0L) { Wm = Whh; k0beg = w * 256; useHin = false; }
  else     { Wm = (w < 2) ? Wih : Whh; k0beg = (w & 1) * 512; useHin = (w < 2); }

  short8 bw[NK][4];
#pragma unroll
  for (int ns = 0; ns < 4; ++ns) {
    int jgl = wgl * 16 + ns * 4 + (nl >> 2);
    int row = (nl & 3) * HD + jgl;                 // gate-major weight row
    const unsigned short* wr = Wm + (size_t)row * HD + kq8 + k0beg;
#pragma unroll
    for (int k = 0; k < NK; ++k) bw[k][ns] = *(const short8*)(wr + k * 32);
  }

  const int bb = (lane >> 4) << 2;
  float* gs = gbuf + w * 4096;

  for (int t = 0; t < TD; ++t) {
    // ---- per-wave decoupled RAW waits (+ WAR bound on w0) ----
    if (L0L) {
      if (t > 0) {
        if (w == 0) wait2(fOwn, t, fCons, t - (NS - 1), lane);
        else        wait1(fOwn, t, lane);
      }
    } else {
      if (useHin) {             // w0/w1: upstream data, typically ready
        if (w == 0) {
          if (t > 0) wait2(fProd, t + 1, fCons, t - (NS - 1), lane);
          else       wait1(fProd, 1, lane);
        } else {
          wait1(fProd, t + 1, lane);
        }
      } else {                  // w2/w3: recurrence-critical
        if (t > 0) wait1(fOwn, t, lane);
      }
    }
    // Slot-reuse invalidate, once per NS steps (cheap: 1/16 of steps).
    if ((t & (NS - 1)) == 0) __builtin_amdgcn_fence(__ATOMIC_ACQUIRE, "agent");

    const unsigned short* A = useHin ? (hinbase + (size_t)(t & (NS - 1)) * BH)
                                     : (hbase + (size_t)((t - 1) & (NS - 1)) * BH);
    const unsigned short* arow = A + nl * HD + kq8 + k0beg;

    f32x4 acc[4][4];
    const f32x4 z4 = {0.f, 0.f, 0.f, 0.f};
#pragma unroll
    for (int ns = 0; ns < 4; ++ns)
#pragma unroll
      for (int mt = 0; mt < 4; ++mt) acc[ns][mt] = z4;

    gemm_bw<NK>(arow, bw, acc);

#pragma unroll
    for (int ns = 0; ns < 4; ++ns) {
      int gn = ns * 16 + nl;
#pragma unroll
      for (int mt = 0; mt < 4; ++mt)
#pragma unroll
        for (int r = 0; r < 4; ++r)
          gs[sw(gn, mt * 16 + bb + r)] = acc[ns][mt][r];
    }
    __syncthreads();  // gbuf ready; also orders h-stores after w0's WAR check

    unsigned short* hout = hbase + (size_t)(t & (NS - 1)) * BH;
#pragma unroll
    for (int it = 0; it < 2; ++it) {
      int item = it * 256 + tid;
      int jp = item >> 6;          // 0..7 pair of j
      int b = item & 63;
      unsigned hv[2];
#pragma unroll
      for (int u2 = 0; u2 < 2; ++u2) {
        int jj = jp * 2 + u2;
        int j = wgl * 16 + jj;
        float p[4];
#pragma unroll
        for (int g = 0; g < 4; ++g) {
          int a = sw(jj * 4 + g, b);
          p[g] = gbuf[a] + gbuf[4096 + a] + gbuf[8192 + a] + gbuf[12288 + a] + bias[g * HD + j];
        }
        if (L0L) {
          const float* xr = strokes + ((size_t)b * TD + t) * 3;
          float x0 = xr[0], x1 = xr[1], x2 = xr[2];
#pragma unroll
          for (int g = 0; g < 4; ++g) {
            const float* wr = Wih0 + (size_t)(g * HD + j) * 3;
            p[g] += x0 * wr[0] + x1 * wr[1] + x2 * wr[2];
          }
        }
        float iv = sigmoidf_(p[0]);
        float fv = sigmoidf_(p[1]);
        float gv = tanhf(p[2]);
        float ov = sigmoidf_(p[3]);
        int ci = j * BD + b;       // CU-private, normal cached RMW
        float cn = fv * c[ci] + iv * gv;
        c[ci] = cn;
        hv[u2] = (unsigned)f2bf(ov * tanhf(cn));
      }
      unsigned packed = hv[0] | (hv[1] << 16);
      // sc1 write-through: MALL is the coherence point consumers fetch from.
      __hip_atomic_store((unsigned*)(hout + (size_t)b * HD + wgl * 16 + jp * 2), packed,
                         __ATOMIC_RELAXED, __HIP_MEMORY_SCOPE_AGENT);
    }
    // Drain own h stores to MALL, sync all waves, then publish (relaxed --
    // NO release/wbl2: the sc1 stores are already at the coherence point).
    asm volatile("s_waitcnt vmcnt(0)" ::: "memory");
    __syncthreads();
    if (tid == 0)
      __hip_atomic_store(fOwn + wgl, t + 1, __ATOMIC_RELAXED, __HIP_MEMORY_SCOPE_AGENT);
  }
}

// ---------------- output projection driver (2 WGs x 64 o-columns) ----------------
__device__ __forceinline__ void run_out(
    int wgo, int tid,
    const unsigned short* __restrict__ h2base,
    const unsigned short* __restrict__ Wo,   // bf16 [128][1024] padded
    const float* __restrict__ bo,
    float* __restrict__ outp, float* gbuf, int* fOwn, const int* fProd) {
  const int lane = tid & 63;
  const int w = tid >> 6;
  const int nl = lane & 15;
  const int kq8 = (lane >> 4) << 3;
  const int k0beg = w * 256;

  short8 bw[8][4];
#pragma unroll
  for (int ns = 0; ns < 4; ++ns) {
    int o = wgo * 64 + ns * 16 + nl;
    const unsigned short* wr = Wo + (size_t)o * HD + kq8 + k0beg;
#pragma unroll
    for (int k = 0; k < 8; ++k) bw[k][ns] = *(const short8*)(wr + k * 32);
  }

  const int bb = (lane >> 4) << 2;
  float* gs = gbuf + w * 4096;

  for (int t = 0; t < TD; ++t) {
    wait1(fProd, t + 1, lane);   // every wave polls independently
    if ((t & (NS - 1)) == 0) __builtin_amdgcn_fence(__ATOMIC_ACQUIRE, "agent");

    const unsigned short* arow = h2base + (size_t)(t & (NS - 1)) * BH + nl * HD + kq8 + k0beg;

    f32x4 acc[4][4];
    const f32x4 z4 = {0.f, 0.f, 0.f, 0.f};
#pragma unroll
    for (int ns = 0; ns < 4; ++ns)
#pragma unroll
      for (int mt = 0; mt < 4; ++mt) acc[ns][mt] = z4;

    gemm_bw<8>(arow, bw, acc);

#pragma unroll
    for (int ns = 0; ns < 4; ++ns) {
      int gn = ns * 16 + nl;
#pragma unroll
      for (int mt = 0; mt < 4; ++mt)
#pragma unroll
        for (int r = 0; r < 4; ++r)
          gs[sw(gn, mt * 16 + bb + r)] = acc[ns][mt][r];
    }
    __syncthreads();

#pragma unroll
    for (int it = 0; it < 16; ++it) {
      int item = it * 256 + tid;
      int ol = item >> 6;
      int b = item & 63;
      int o = wgo * 64 + ol;
      int a = sw(ol, b);
      float v = gbuf[a] + gbuf[4096 + a] + gbuf[8192 + a] + gbuf[12288 + a] + bo[o];
      if (o < 121) outp[((size_t)b * TD + t) * 121 + o] = v;
    }
    // A-reads of h2[t] fully retired (gemm drains to vmcnt 0) -> WAR signal
    // for layer2.
    asm volatile("s_waitcnt vmcnt(0)" ::: "memory");
    __syncthreads();
    if (tid == 0)
      __hip_atomic_store(fOwn + wgo, t + 1, __ATOMIC_RELAXED, __HIP_MEMORY_SCOPE_AGENT);
  }
}

// ---------------- main kernel ----------------
// XCD-partitioned mapping (HW-measured round-robin dispatch: XCD = blockIdx%8):
//   XCDs 0,1 -> layer0 (32 WGs each); XCDs 2,3 -> layer1; XCDs 4,5 -> layer2;
//   XCD 6 slots 0,1 -> out-proj; everything else exits immediately.
// 256 blocks at 1 block/CU -> all co-resident regardless of actual mapping;
// if the %8 assumption is wrong we only lose locality, never correctness.
__global__ void __launch_bounds__(256, 1)
lstm_main(const float* __restrict__ strokes, const float* __restrict__ Wih0,
          float* __restrict__ outp, void* __restrict__ wsv) {
  __shared__ float gbuf[16384];  // 64 KB: 4 K-slices x [64 gn][64 b]
  unsigned short* u = (unsigned short*)wsv;
  float* fr = (float*)((char*)wsv + FBYTE_BASE);
  int* flags = (int*)fr + FOFF_FLAGS;
  int* f0 = flags;          // layer0 per-WG progress (64)
  int* f1 = flags + 64;     // layer1
  int* f2 = flags + 128;    // layer2
  int* f3 = flags + 192;    // out (2 real + 62 preset huge)

  const int xcd = blockIdx.x & 7;
  const int slot = blockIdx.x >> 3;   // 0..31
  const int tid = threadIdx.x;

  if (xcd < 2) {
    int wgl = ((xcd & 1) << 5) + slot;
    run_layer<true>(wgl, tid, nullptr, u + OFF_H0, fr + FOFF_C0,
                    nullptr, u + OFF_WHH0, fr + FOFF_B0, strokes, Wih0, gbuf,
                    f0, nullptr, f1);
  } else if (xcd < 4) {
    int wgl = ((xcd & 1) << 5) + slot;
    run_layer<false>(wgl, tid, u + OFF_H0, u + OFF_H1, fr + FOFF_C1,
                     u + OFF_WIH1, u + OFF_WHH1, fr + FOFF_B1, nullptr, nullptr, gbuf,
                     f1, f0, f2);
  } else if (xcd < 6) {
    int wgl = ((xcd & 1) << 5) + slot;
    run_layer<false>(wgl, tid, u + OFF_H1, u + OFF_H2, fr + FOFF_C2,
                     u + OFF_WIH2, u + OFF_WHH2, fr + FOFF_B2, nullptr, nullptr, gbuf,
                     f2, f1, f3);
  } else if (xcd == 6 && slot < 2) {
    run_out(slot, tid, u + OFF_H2, u + OFF_WOUT, fr + FOFF_BOUT, outp, gbuf,
            f3, f2);
  }
  // else: idle block, exit immediately
}

extern "C" void kernel_launch(void* const* d_in, const int* in_sizes, int n_in,
                              void* d_out, int out_size, void* d_ws, size_t ws_size,
                              hipStream_t stream) {
  const float* strokes = (const float*)d_in[0];
  const float* Wih0 = (const float*)d_in[1];
  const float* Whh0 = (const float*)d_in[2];
  const float* bih0 = (const float*)d_in[3];
  const float* bhh0 = (const float*)d_in[4];
  const float* Wih1 = (const float*)d_in[5];
  const float* Whh1 = (const float*)d_in[6];
  const float* bih1 = (const float*)d_in[7];
  const float* bhh1 = (const float*)d_in[8];
  const float* Wih2 = (const float*)d_in[9];
  const float* Whh2 = (const float*)d_in[10];
  const float* bih2 = (const float*)d_in[11];
  const float* bhh2 = (const float*)d_in[12];
  const float* Wout = (const float*)d_in[13];
  const float* bout = (const float*)d_in[14];
  float* outp = (float*)d_out;

  hipLaunchKernelGGL(prep_kernel, dim3(4096), dim3(256), 0, stream,
                     Whh0, Wih1, Whh1, Wih2, Whh2, Wout,
                     bih0, bhh0, bih1, bhh1, bih2, bhh2, bout, d_ws);

  hipLaunchKernelGGL(lstm_main, dim3(NBLK), dim3(256), 0, stream,
                     strokes, Wih0, outp, d_ws);
}

// Round 6
// 7452.235 us; speedup vs baseline: 1.5865x; 1.1840x over previous
//
#include <hip/hip_runtime.h>

typedef __attribute__((ext_vector_type(8))) short short8;
typedef __attribute__((ext_vector_type(4))) float f32x4;
typedef __attribute__((ext_vector_type(4))) int int4v;

#define HD 1024
#define BD 64
#define TD 512
#define BH 65536UL  // one h slot: 64*1024 ushorts (128 KB)
#define NS 16       // h slot rotation depth == fence period
#define NBLK 256    // 1 block/CU; XCD-partitioned mapping inside
#define FSTRIDE 32  // flag padding: 32 ints = 128 B = one line per WG

// ---------------- workspace layout ----------------
#define M4 4194304UL
#define OFF_WHH0 0UL
#define OFF_WIH1 (1UL * M4)
#define OFF_WHH1 (2UL * M4)
#define OFF_WIH2 (3UL * M4)
#define OFF_WHH2 (4UL * M4)
#define OFF_WOUT (5UL * M4)                 // 128 x 1024 (padded rows zeroed)
#define OFF_H0   (OFF_WOUT + 131072UL)      // [NS slots][64][1024] per layer
#define OFF_H1   (OFF_H0 + (NS * BH))
#define OFF_H2   (OFF_H1 + (NS * BH))
#define USHORT_TOTAL (OFF_H2 + (NS * BH))   // 24248320
#define FBYTE_BASE (USHORT_TOTAL * 2UL)
#define FOFF_C0 0UL                          // c stored [j][b] (transposed)
#define FOFF_C1 65536UL
#define FOFF_C2 131072UL
#define FOFF_B0 196608UL                     // combined biases b_ih+b_hh [4096]
#define FOFF_B1 200704UL
#define FOFF_B2 204800UL
#define FOFF_BOUT 208896UL                   // [128], pad zeroed
#define FOFF_FLAGS 209024UL                  // 4 arrays x 64 WGs x FSTRIDE ints (padded)
#define PREP_TOTAL 24465536UL

__device__ __forceinline__ unsigned short f2bf(float f) {
  union { float f; unsigned u; } v; v.f = f;
  unsigned r = v.u + 0x7fffu + ((v.u >> 16) & 1u);  // RNE
  return (unsigned short)(r >> 16);
}
__device__ __forceinline__ float sigmoidf_(float x) {
  return 1.0f / (1.0f + __expf(-x));
}
// LDS bank swizzle (unchanged).
__device__ __forceinline__ int sw(int gn, int b) {
  return gn * 64 + (b ^ (((gn & 7) << 2) | ((gn >> 3) & 3)));
}

// A-matrix load: plain cached 16B load (L2-hit confirmed by R5 FETCH drop).
// Coherence contract (HW-validated R4/R5): producers sc1-write-through h and
// drain vmcnt(0) before the relaxed flag store; NS=16 slot rotation + one
// acquire fence per 16-step window guarantees no stale L2/L1 line can serve
// a current-slot read.
__device__ __forceinline__ void gload16(int4v& dst, const unsigned short* p) {
  asm volatile("global_load_dwordx4 %0, %1, off" : "=v"(dst) : "v"(p));
}
#define AWAIT_N(N, a0, a1, a2, a3) \
  asm volatile("s_waitcnt vmcnt(" #N ")" : "+v"(a0), "+v"(a1), "+v"(a2), "+v"(a3))

// ---------------- padded per-WG progress flags ----------------
// flag[wg] lives at its OWN 128-B line (FSTRIDE ints): the 64 producer
// stores per layer per step hit 64 distinct lines -> no MALL line-RMW
// serialization (the R0-R5 invariant poison). Pollers: lane i reads
// flag[i] (stride 128 B). Only 2 waves per WG poll globally; the other
// waves spin on an LDS mailbox. s_sleep(8) caps poll read traffic.
__device__ __forceinline__ void wait1p(const int* fa, int ka, int lane) {
  const int* pa = fa + lane * FSTRIDE;
  for (;;) {
    int va;
    asm volatile("global_load_dword %0, %1, off sc1" : "=v"(va) : "v"(pa));
    asm volatile("s_waitcnt vmcnt(0)" : "+v"(va));
    if (__all(va >= ka)) return;
    __builtin_amdgcn_s_sleep(8);
  }
}
__device__ __forceinline__ void wait2p(const int* fa, int ka, const int* fb, int kb, int lane) {
  const int* pa = fa + lane * FSTRIDE;
  const int* pb = fb + lane * FSTRIDE;
  for (;;) {
    int va, vb;
    asm volatile("global_load_dword %0, %1, off sc1" : "=v"(va) : "v"(pa));
    asm volatile("global_load_dword %0, %1, off sc1" : "=v"(vb) : "v"(pb));
    asm volatile("s_waitcnt vmcnt(0)" : "+v"(va), "+v"(vb));
    if (__all(va >= ka) && __all(vb >= kb)) return;
    __builtin_amdgcn_s_sleep(8);
  }
}
// LDS mailbox: poller wave publishes step t; sibling wave spins locally.
__device__ __forceinline__ void mb_store(int* m, int t, int lane) {
  if (lane == 0)
    __hip_atomic_store(m, t, __ATOMIC_RELEASE, __HIP_MEMORY_SCOPE_WORKGROUP);
}
__device__ __forceinline__ void mb_spin(const int* m, int t) {
  while (__hip_atomic_load(m, __ATOMIC_ACQUIRE, __HIP_MEMORY_SCOPE_WORKGROUP) < t)
    __builtin_amdgcn_s_sleep(1);
}

// ---------------- prep ----------------
__global__ void prep_kernel(const float* __restrict__ Whh0, const float* __restrict__ Wih1,
                            const float* __restrict__ Whh1, const float* __restrict__ Wih2,
                            const float* __restrict__ Whh2, const float* __restrict__ Wout,
                            const float* __restrict__ bih0, const float* __restrict__ bhh0,
                            const float* __restrict__ bih1, const float* __restrict__ bhh1,
                            const float* __restrict__ bih2, const float* __restrict__ bhh2,
                            const float* __restrict__ bout, void* wsv) {
  unsigned short* u = (unsigned short*)wsv;
  float* fr = (float*)((char*)wsv + FBYTE_BASE);
  int* fi = (int*)fr;
  size_t stride = (size_t)gridDim.x * blockDim.x;
  for (size_t i = (size_t)blockIdx.x * blockDim.x + threadIdx.x; i < PREP_TOTAL; i += stride) {
    if (i < 20971520UL) {
      size_t which = i >> 22;
      size_t off = i & (M4 - 1UL);
      const float* src = (which == 0) ? Whh0 : (which == 1) ? Wih1 :
                         (which == 2) ? Whh1 : (which == 3) ? Wih2 : Whh2;
      u[i] = f2bf(src[off]);
    } else if (i < 21102592UL) {
      size_t k = i - 20971520UL;
      size_t o = k >> 10, kk = k & 1023UL;
      u[i] = (o < 121) ? f2bf(Wout[o * 1024UL + kk]) : (unsigned short)0;
    } else if (i < 24248320UL) {
      u[i] = 0;                                   // zero all NS h slots x 3 layers
    } else if (i < 24444928UL) {
      fr[i - 24248320UL] = 0.0f;                  // zero c0,c1,c2
    } else if (i < 24457216UL) {
      size_t k = i - 24444928UL;
      size_t l = k >> 12, n = k & 4095UL;
      const float* bi = (l == 0) ? bih0 : (l == 1) ? bih1 : bih2;
      const float* bh = (l == 0) ? bhh0 : (l == 1) ? bhh1 : bhh2;
      fr[FOFF_B0 + l * 4096UL + n] = bi[n] + bh[n];
    } else if (i < 24457344UL) {
      size_t k = i - 24457216UL;
      fr[FOFF_BOUT + k] = (k < 121) ? bout[k] : 0.0f;
    } else {
      size_t k = i - 24457344UL;                  // 8192 padded flag ints
      size_t a = k >> 11;                         // array 0..3
      size_t wg = (k & 2047UL) >> 5;              // WG slot within array
      fi[FOFF_FLAGS + k] = (a < 3 || wg < 2) ? 0 : (1 << 29);
    }
  }
}

// ---------------- GEMM slice: register B, 6-deep explicit-vmcnt pipelined A ----------------
template <int NK>
__device__ __forceinline__ void gemm_bw(const unsigned short* __restrict__ arow,
                                        const short8 (&bw)[NK][4],
                                        f32x4 (&acc)[4][4]) {
  static_assert(NK >= 6, "pipeline depth");
  int4v ap[6][4];
#pragma unroll
  for (int g = 0; g < 6; ++g)
#pragma unroll
    for (int mt = 0; mt < 4; ++mt)
      gload16(ap[g][mt], arow + mt * 16 * HD + g * 32);
#pragma unroll
  for (int k = 0; k < NK; ++k) {
    const int s = k % 6;
    if (k <= NK - 6)          { AWAIT_N(20, ap[s][0], ap[s][1], ap[s][2], ap[s][3]); }
    else if (NK - 1 - k == 4) { AWAIT_N(16, ap[s][0], ap[s][1], ap[s][2], ap[s][3]); }
    else if (NK - 1 - k == 3) { AWAIT_N(12, ap[s][0], ap[s][1], ap[s][2], ap[s][3]); }
    else if (NK - 1 - k == 2) { AWAIT_N(8,  ap[s][0], ap[s][1], ap[s][2], ap[s][3]); }
    else if (NK - 1 - k == 1) { AWAIT_N(4,  ap[s][0], ap[s][1], ap[s][2], ap[s][3]); }
    else                      { AWAIT_N(0,  ap[s][0], ap[s][1], ap[s][2], ap[s][3]); }
#pragma unroll
    for (int mt = 0; mt < 4; ++mt) {
      short8 a = *(short8*)&ap[s][mt];
#pragma unroll
      for (int ns = 0; ns < 4; ++ns)
        acc[ns][mt] = __builtin_amdgcn_mfma_f32_16x16x32_bf16(a, bw[k][ns], acc[ns][mt], 0, 0, 0);
    }
    if (k + 6 < NK) {
#pragma unroll
      for (int mt = 0; mt < 4; ++mt)
        gload16(ap[s][mt], arow + mt * 16 * HD + (k + 6) * 32);
    }
  }
}

// ---------------- persistent-weight layer driver (dataflow-synced, cached A) ----------------
// Sync topology per WG (2 global pollers + 2 LDS spinners):
//   w0: polls fProd(>=t+1)[non-L0]/fOwn(>=t)[L0] AND fCons(>=t-15) -> mb[0]
//   w1: spins mb[0] >= t
//   w2: polls fOwn >= t -> mb[1]
//   w3: spins mb[1] >= t
template <bool L0L>
__device__ __forceinline__ void run_layer(
    int wgl, int tid,
    const unsigned short* __restrict__ hinbase,  // upstream h (NS slots), null for L0
    unsigned short* __restrict__ hbase,          // own h (NS slots)
    float* __restrict__ c,                       // [1024][64] fp32 transposed
    const unsigned short* __restrict__ Wih,      // null for L0
    const unsigned short* __restrict__ Whh,
    const float* __restrict__ bias,
    const float* __restrict__ strokes,           // L0 only
    const float* __restrict__ Wih0,              // L0 only, fp32 [4096][3]
    float* gbuf, int* mb, int* fOwn, const int* fProd, const int* fCons) {
  constexpr int NK = L0L ? 8 : 16;
  const int lane = tid & 63;
  const int w = tid >> 6;
  const int nl = lane & 15;
  const int kq8 = (lane >> 4) << 3;

  const unsigned short* Wm;
  int k0beg;
  bool useHin;
  if (L0L) { Wm = Whh; k0beg = w * 256; useHin = false; }
  else     { Wm = (w < 2) ? Wih : Whh; k0beg = (w & 1) * 512; useHin = (w < 2); }

  short8 bw[NK][4];
#pragma unroll
  for (int ns = 0; ns < 4; ++ns) {
    int jgl = wgl * 16 + ns * 4 + (nl >> 2);
    int row = (nl & 3) * HD + jgl;                 // gate-major weight row
    const unsigned short* wr = Wm + (size_t)row * HD + kq8 + k0beg;
#pragma unroll
    for (int k = 0; k < NK; ++k) bw[k][ns] = *(const short8*)(wr + k * 32);
  }

  const int bb = (lane >> 4) << 2;
  float* gs = gbuf + w * 4096;

  for (int t = 0; t < TD; ++t) {
    // ---- sync: 2 global pollers + 2 LDS spinners ----
    if (L0L) {
      if (t > 0) {
        if (w == 0)      { wait2p(fOwn, t, fCons, t - (NS - 1), lane); mb_store(mb + 0, t, lane); }
        else if (w == 1) { mb_spin(mb + 0, t); }
        else if (w == 2) { wait1p(fOwn, t, lane); mb_store(mb + 1, t, lane); }
        else             { mb_spin(mb + 1, t); }
      }
    } else {
      if (w == 0) {
        if (t > 0) wait2p(fProd, t + 1, fCons, t - (NS - 1), lane);
        else       wait1p(fProd, 1, lane);
        mb_store(mb + 0, t, lane);
      } else if (w == 1) {
        mb_spin(mb + 0, t);
      } else if (w == 2) {
        if (t > 0) { wait1p(fOwn, t, lane); mb_store(mb + 1, t, lane); }
      } else {
        if (t > 0) mb_spin(mb + 1, t);
      }
    }
    // Slot-reuse invalidate, once per NS steps (cheap: 1/16 of steps).
    if ((t & (NS - 1)) == 0) __builtin_amdgcn_fence(__ATOMIC_ACQUIRE, "agent");

    const unsigned short* A = useHin ? (hinbase + (size_t)(t & (NS - 1)) * BH)
                                     : (hbase + (size_t)((t - 1) & (NS - 1)) * BH);
    const unsigned short* arow = A + nl * HD + kq8 + k0beg;

    f32x4 acc[4][4];
    const f32x4 z4 = {0.f, 0.f, 0.f, 0.f};
#pragma unroll
    for (int ns = 0; ns < 4; ++ns)
#pragma unroll
      for (int mt = 0; mt < 4; ++mt) acc[ns][mt] = z4;

    gemm_bw<NK>(arow, bw, acc);

#pragma unroll
    for (int ns = 0; ns < 4; ++ns) {
      int gn = ns * 16 + nl;
#pragma unroll
      for (int mt = 0; mt < 4; ++mt)
#pragma unroll
        for (int r = 0; r < 4; ++r)
          gs[sw(gn, mt * 16 + bb + r)] = acc[ns][mt][r];
    }
    __syncthreads();  // gbuf ready; also orders h-stores after w0's WAR check

    unsigned short* hout = hbase + (size_t)(t & (NS - 1)) * BH;
#pragma unroll
    for (int it = 0; it < 2; ++it) {
      int item = it * 256 + tid;
      int jp = item >> 6;          // 0..7 pair of j
      int b = item & 63;
      unsigned hv[2];
#pragma unroll
      for (int u2 = 0; u2 < 2; ++u2) {
        int jj = jp * 2 + u2;
        int j = wgl * 16 + jj;
        float p[4];
#pragma unroll
        for (int g = 0; g < 4; ++g) {
          int a = sw(jj * 4 + g, b);
          p[g] = gbuf[a] + gbuf[4096 + a] + gbuf[8192 + a] + gbuf[12288 + a] + bias[g * HD + j];
        }
        if (L0L) {
          const float* xr = strokes + ((size_t)b * TD + t) * 3;
          float x0 = xr[0], x1 = xr[1], x2 = xr[2];
#pragma unroll
          for (int g = 0; g < 4; ++g) {
            const float* wr = Wih0 + (size_t)(g * HD + j) * 3;
            p[g] += x0 * wr[0] + x1 * wr[1] + x2 * wr[2];
          }
        }
        float iv = sigmoidf_(p[0]);
        float fv = sigmoidf_(p[1]);
        float gv = tanhf(p[2]);
        float ov = sigmoidf_(p[3]);
        int ci = j * BD + b;       // CU-private, normal cached RMW
        float cn = fv * c[ci] + iv * gv;
        c[ci] = cn;
        hv[u2] = (unsigned)f2bf(ov * tanhf(cn));
      }
      unsigned packed = hv[0] | (hv[1] << 16);
      // sc1 write-through: MALL is the coherence point consumers fetch from.
      __hip_atomic_store((unsigned*)(hout + (size_t)b * HD + wgl * 16 + jp * 2), packed,
                         __ATOMIC_RELAXED, __HIP_MEMORY_SCOPE_AGENT);
    }
    // Drain own h stores to MALL, sync all waves, then publish the padded
    // per-WG flag (relaxed; its line is private to this WG -> no line RMW
    // contention at MALL).
    asm volatile("s_waitcnt vmcnt(0)" ::: "memory");
    __syncthreads();
    if (tid == 0)
      __hip_atomic_store(fOwn + wgl * FSTRIDE, t + 1, __ATOMIC_RELAXED, __HIP_MEMORY_SCOPE_AGENT);
  }
}

// ---------------- output projection driver (2 WGs x 64 o-columns) ----------------
__device__ __forceinline__ void run_out(
    int wgo, int tid,
    const unsigned short* __restrict__ h2base,
    const unsigned short* __restrict__ Wo,   // bf16 [128][1024] padded
    const float* __restrict__ bo,
    float* __restrict__ outp, float* gbuf, int* mb, int* fOwn, const int* fProd) {
  const int lane = tid & 63;
  const int w = tid >> 6;
  const int nl = lane & 15;
  const int kq8 = (lane >> 4) << 3;
  const int k0beg = w * 256;

  short8 bw[8][4];
#pragma unroll
  for (int ns = 0; ns < 4; ++ns) {
    int o = wgo * 64 + ns * 16 + nl;
    const unsigned short* wr = Wo + (size_t)o * HD + kq8 + k0beg;
#pragma unroll
    for (int k = 0; k < 8; ++k) bw[k][ns] = *(const short8*)(wr + k * 32);
  }

  const int bb = (lane >> 4) << 2;
  float* gs = gbuf + w * 4096;

  for (int t = 0; t < TD; ++t) {
    if (w == 0) { wait1p(fProd, t + 1, lane); mb_store(mb + 0, t, lane); }
    else        { mb_spin(mb + 0, t); }
    if ((t & (NS - 1)) == 0) __builtin_amdgcn_fence(__ATOMIC_ACQUIRE, "agent");

    const unsigned short* arow = h2base + (size_t)(t & (NS - 1)) * BH + nl * HD + kq8 + k0beg;

    f32x4 acc[4][4];
    const f32x4 z4 = {0.f, 0.f, 0.f, 0.f};
#pragma unroll
    for (int ns = 0; ns < 4; ++ns)
#pragma unroll
      for (int mt = 0; mt < 4; ++mt) acc[ns][mt] = z4;

    gemm_bw<8>(arow, bw, acc);

#pragma unroll
    for (int ns = 0; ns < 4; ++ns) {
      int gn = ns * 16 + nl;
#pragma unroll
      for (int mt = 0; mt < 4; ++mt)
#pragma unroll
        for (int r = 0; r < 4; ++r)
          gs[sw(gn, mt * 16 + bb + r)] = acc[ns][mt][r];
    }
    __syncthreads();

#pragma unroll
    for (int it = 0; it < 16; ++it) {
      int item = it * 256 + tid;
      int ol = item >> 6;
      int b = item & 63;
      int o = wgo * 64 + ol;
      int a = sw(ol, b);
      float v = gbuf[a] + gbuf[4096 + a] + gbuf[8192 + a] + gbuf[12288 + a] + bo[o];
      if (o < 121) outp[((size_t)b * TD + t) * 121 + o] = v;
    }
    // A-reads of h2[t] fully retired (gemm drains to vmcnt 0) -> WAR signal
    // for layer2.
    asm volatile("s_waitcnt vmcnt(0)" ::: "memory");
    __syncthreads();
    if (tid == 0)
      __hip_atomic_store(fOwn + wgo * FSTRIDE, t + 1, __ATOMIC_RELAXED, __HIP_MEMORY_SCOPE_AGENT);
  }
}

// ---------------- main kernel ----------------
// XCD-partitioned mapping (XCD = blockIdx%8): XCDs 0,1 -> layer0; 2,3 ->
// layer1; 4,5 -> layer2; XCD 6 slots 0,1 -> out-proj; rest exit.
// 256 blocks at 1 block/CU -> all co-resident regardless of actual mapping.
__global__ void __launch_bounds__(256, 1)
lstm_main(const float* __restrict__ strokes, const float* __restrict__ Wih0,
          float* __restrict__ outp, void* __restrict__ wsv) {
  __shared__ float gbuf[16384];  // 64 KB: 4 K-slices x [64 gn][64 b]
  __shared__ int mbx[2];         // LDS mailboxes (poller -> spinner)
  unsigned short* u = (unsigned short*)wsv;
  float* fr = (float*)((char*)wsv + FBYTE_BASE);
  int* flags = (int*)fr + FOFF_FLAGS;
  int* f0 = flags;               // layer0, padded (64 x FSTRIDE)
  int* f1 = flags + 2048;        // layer1
  int* f2 = flags + 4096;        // layer2
  int* f3 = flags + 6144;        // out (2 real + 62 preset huge)

  const int xcd = blockIdx.x & 7;
  const int slot = blockIdx.x >> 3;   // 0..31
  const int tid = threadIdx.x;

  if (tid == 0) { mbx[0] = -1; mbx[1] = -1; }
  __syncthreads();

  if (xcd < 2) {
    int wgl = ((xcd & 1) << 5) + slot;
    run_layer<true>(wgl, tid, nullptr, u + OFF_H0, fr + FOFF_C0,
                    nullptr, u + OFF_WHH0, fr + FOFF_B0, strokes, Wih0, gbuf,
                    mbx, f0, nullptr, f1);
  } else if (xcd < 4) {
    int wgl = ((xcd & 1) << 5) + slot;
    run_layer<false>(wgl, tid, u + OFF_H0, u + OFF_H1, fr + FOFF_C1,
                     u + OFF_WIH1, u + OFF_WHH1, fr + FOFF_B1, nullptr, nullptr, gbuf,
                     mbx, f1, f0, f2);
  } else if (xcd < 6) {
    int wgl = ((xcd & 1) << 5) + slot;
    run_layer<false>(wgl, tid, u + OFF_H1, u + OFF_H2, fr + FOFF_C2,
                     u + OFF_WIH2, u + OFF_WHH2, fr + FOFF_B2, nullptr, nullptr, gbuf,
                     mbx, f2, f1, f3);
  } else if (xcd == 6 && slot < 2) {
    run_out(slot, tid, u + OFF_H2, u + OFF_WOUT, fr + FOFF_BOUT, outp, gbuf,
            mbx, f3, f2);
  }
  // else: idle block, exit immediately
}

extern "C" void kernel_launch(void* const* d_in, const int* in_sizes, int n_in,
                              void* d_out, int out_size, void* d_ws, size_t ws_size,
                              hipStream_t stream) {
  const float* strokes = (const float*)d_in[0];
  const float* Wih0 = (const float*)d_in[1];
  const float* Whh0 = (const float*)d_in[2];
  const float* bih0 = (const float*)d_in[3];
  const float* bhh0 = (const float*)d_in[4];
  const float* Wih1 = (const float*)d_in[5];
  const float* Whh1 = (const float*)d_in[6];
  const float* bih1 = (const float*)d_in[7];
  const float* bhh1 = (const float*)d_in[8];
  const float* Wih2 = (const float*)d_in[9];
  const float* Whh2 = (const float*)d_in[10];
  const float* bih2 = (const float*)d_in[11];
  const float* bhh2 = (const float*)d_in[12];
  const float* Wout = (const float*)d_in[13];
  const float* bout = (const float*)d_in[14];
  float* outp = (float*)d_out;

  hipLaunchKernelGGL(prep_kernel, dim3(4096), dim3(256), 0, stream,
                     Whh0, Wih1, Whh1, Wih2, Whh2, Wout,
                     bih0, bhh0, bih1, bhh1, bih2, bhh2, bout, d_ws);

  hipLaunchKernelGGL(lstm_main, dim3(NBLK), dim3(256), 0, stream,
                     strokes, Wih0, outp, d_ws);
}